// Round 5
// baseline (83.173 us; speedup 1.0000x reference)
//
#include <hip/hip_runtime.h>
#include <math.h>

// dims: B=16 K=1 NC=64 NR=4 RF=4 L=8 M=256 N=1024 BS_TDD=16 RIS_TDD=16
static constexpr double TWO_PI_D = 6.283185307179586476925287;

// workspace offsets (floats)
static constexpr size_t OFF_THRE = 0;          // theta_re [l][c][n]          524288
static constexpr size_t OFF_THIM = 524288;     // theta_im                    524288
static constexpr size_t OFF_FBF  = 1048576;    // F bf16 [c][comp][lf][m]     1048576 shorts
static constexpr size_t OFF_WTBF = 1572864;    // WT bf16 [c][comp][lf][n]    4194304 shorts
static constexpr size_t OFF_Y0P  = 3670016;    // y0 partials [5][c][row][lf][2] 1310720
static constexpr size_t OFF_X    = 4980736;    // x [b][c][rf][t]             262144
static constexpr size_t WS_FLOATS = 5242880;   // 21 MB

typedef __attribute__((ext_vector_type(8))) short short8;
typedef __attribute__((ext_vector_type(4))) float f32x4;

__device__ __forceinline__ double fm_of(int c){
  return ((double)(c + 1) - 32.5) * (1.0e9 / 64.0) + 1.0e11;
}
__device__ __forceinline__ unsigned short f2bf(float x){
  unsigned int u = __float_as_uint(x);
  return (unsigned short)((u + 0x7FFFu + ((u >> 16) & 1u)) >> 16);
}

// theta (+-1 sign * TTD phase) and F (exp(i SA)/16 * TTD phase), TTD sincos via LDS table
__global__ __launch_bounds__(256) void k_prep(
    const float* __restrict__ P1, const float* __restrict__ P2,
    const float* __restrict__ PT, const float* __restrict__ SA,
    const float* __restrict__ ST,
    float* __restrict__ tre, float* __restrict__ tim, unsigned short* __restrict__ Fbf)
{
  __shared__ double tcs[16], tsn[16];
  int bid = blockIdx.x, tid = threadIdx.x;
  const float TWO_PI_F = 6.2831855f, SEG_F = 3.1415927f;
  if (bid < 2048){                                   // theta: (l,c, n-quarter)
    int l = bid >> 8, c = (bid >> 2) & 63, n0 = (bid & 3) * 256;
    if (tid < 4){
      int ris = (n0 >> 6) + tid;
      double a1 = 5.0e-9 / (1.0 + exp((double)(-PT[l * 16 + ris])));
      sincos(TWO_PI_D * fm_of(c) * a1, &tsn[tid], &tcs[tid]);
    }
    __syncthreads();
    int n = n0 + tid;
    float p1 = P1[l * 1024 + n], p2 = P2[l * 1024 + n];
    int k1 = (int)floorf((TWO_PI_F * p1) / SEG_F);   // BIT=1 -> exp(i*k*pi)=+-1
    int k2 = (int)floorf((TWO_PI_F * p2) / SEG_F);
    float s = ((k1 + k2) & 1) ? -1.f : 1.f;
    int t = (l * 64 + c) * 1024 + n;
    int ti = tid >> 6;
    tre[t] = s * (float)tcs[ti];
    tim[t] = s * (float)tsn[ti];
  } else {                                           // F: (l,c,f) x m
    int bid2 = bid - 2048;
    int l = bid2 >> 8, c = (bid2 >> 2) & 63, f = bid2 & 3;
    int m = tid;
    if (tid < 16){
      double bdel = 5.0e-9 / (1.0 + exp((double)(-ST[((l * 64 + c) * 16 + tid) * 4 + f])));
      sincos(TWO_PI_D * fm_of(c) * bdel, &tsn[tid], &tcs[tid]);
    }
    __syncthreads();
    float sa_ = SA[(size_t)((l * 64 + c) * 256 + m) * 4 + f];
    float ssa, csa;
    sincosf(sa_, &ssa, &csa);                        // exact split: exp(iSA)*exp(i2pi f tau)
    float cb = (float)tcs[m >> 4], sb = (float)tsn[m >> 4];
    size_t base = ((size_t)(c * 2) * 32 + (l * 4 + f)) * 256 + m;
    Fbf[base]        = f2bf((csa * cb - ssa * sb) * 0.0625f);
    Fbf[base + 8192] = f2bf((csa * sb + ssa * cb) * 0.0625f);
  }
}

// WT[c,comp,lf,n] (bf16) = theta[l,c,n] * sum_m H_BR[c,n,m] * F[l,c,m,f]
// LDS-free MFMA stream, explicit 2-stage register double-buffer.
// grid 2048 = (c, 32 n-chunks of 32 rows); 4 waves = (lftile, rowhalf); wave: 16 rows x 16 lf.
__global__ __launch_bounds__(256) void k_W(
    const float* __restrict__ Hre, const float* __restrict__ Him,
    const unsigned short* __restrict__ Fbf,
    const float* __restrict__ tre, const float* __restrict__ tim,
    unsigned short* __restrict__ WTbf)
{
  const int bid = blockIdx.x;
  const int c = bid >> 5;
  const int n0 = (bid & 31) * 32;
  const int lane = threadIdx.x & 63, w = threadIdx.x >> 6;
  const int lftile = w & 1, rh = w >> 1;
  const int nt = n0 + rh * 16;                // this wave's 16 rows
  const int kq = lane >> 4, rm = lane & 15;
  const int lf = lftile * 16 + rm;

  const size_t arow = ((size_t)c * 1024 + nt + rm) * 256 + kq * 8;
  const float* hr = Hre + arow;
  const float* hi = Him + arow;
  const unsigned short* fr = Fbf + (size_t)c * 16384 + (size_t)lf * 256 + kq * 8;
  const unsigned short* fi = fr + 8192;

  f32x4 accRe = {0.f,0.f,0.f,0.f}, accIm = {0.f,0.f,0.f,0.f};

  float4 r0A, r1A, i0A, i1A; short8 brA, biA;
  float4 r0B, r1B, i0B, i1B; short8 brB, biB;

#define LOADK(S, CK) do {                              \
    const int mo_ = (CK) * 32;                         \
    r0##S = *(const float4*)(hr + mo_);                \
    r1##S = *(const float4*)(hr + mo_ + 4);            \
    i0##S = *(const float4*)(hi + mo_);                \
    i1##S = *(const float4*)(hi + mo_ + 4);            \
    br##S = *(const short8*)(fr + mo_);                \
    bi##S = *(const short8*)(fi + mo_);                \
  } while (0)

#define COMPK(S) do {                                                                 \
    short8 are_, aim_, bin_;                                                          \
    are_[0]=(short)f2bf(r0##S.x); are_[1]=(short)f2bf(r0##S.y);                       \
    are_[2]=(short)f2bf(r0##S.z); are_[3]=(short)f2bf(r0##S.w);                       \
    are_[4]=(short)f2bf(r1##S.x); are_[5]=(short)f2bf(r1##S.y);                       \
    are_[6]=(short)f2bf(r1##S.z); are_[7]=(short)f2bf(r1##S.w);                       \
    aim_[0]=(short)f2bf(i0##S.x); aim_[1]=(short)f2bf(i0##S.y);                       \
    aim_[2]=(short)f2bf(i0##S.z); aim_[3]=(short)f2bf(i0##S.w);                       \
    aim_[4]=(short)f2bf(i1##S.x); aim_[5]=(short)f2bf(i1##S.y);                       \
    aim_[6]=(short)f2bf(i1##S.z); aim_[7]=(short)f2bf(i1##S.w);                       \
    _Pragma("unroll")                                                                 \
    for (int j = 0; j < 8; j++) bin_[j] = bi##S[j] ^ (short)0x8000;                   \
    accRe = __builtin_amdgcn_mfma_f32_16x16x32_bf16(are_, br##S, accRe, 0, 0, 0);     \
    accRe = __builtin_amdgcn_mfma_f32_16x16x32_bf16(aim_, bin_,  accRe, 0, 0, 0);     \
    accIm = __builtin_amdgcn_mfma_f32_16x16x32_bf16(are_, bi##S, accIm, 0, 0, 0);     \
    accIm = __builtin_amdgcn_mfma_f32_16x16x32_bf16(aim_, br##S, accIm, 0, 0, 0);     \
  } while (0)

  LOADK(A, 0);
  LOADK(B, 1);
  COMPK(A);          // during this, loads(1) in flight
  LOADK(A, 2);
  COMPK(B);          // loads(2) in flight
  LOADK(B, 3);
  COMPK(A);
  LOADK(A, 4);
  COMPK(B);
  LOADK(B, 5);
  COMPK(A);
  LOADK(A, 6);
  COMPK(B);
  LOADK(B, 7);
  COMPK(A);
  COMPK(B);

#undef LOADK
#undef COMPK

  // epilogue: theta-multiply, pack bf16, store WT[c][comp][lf][n]
  // C layout: col(lf)=lane&15, row(n)=nt+kq*4+r
  {
    const int l = lf >> 2;
    unsigned short pr[4], pi_[4];
    #pragma unroll
    for (int r = 0; r < 4; r++){
      size_t ti = (size_t)(l * 64 + c) * 1024 + nt + kq * 4 + r;
      float wr = tre[ti], wi = tim[ti];
      float xr = accRe[r], xi = accIm[r];
      pr[r]  = f2bf(wr * xr - wi * xi);
      pi_[r] = f2bf(wr * xi + wi * xr);
    }
    size_t rb = ((size_t)(c * 2) * 32 + lf) * 1024 + nt + kq * 4;
    *(uint2*)(WTbf + rb) =
        make_uint2((unsigned)pr[0] | ((unsigned)pr[1] << 16),
                   (unsigned)pr[2] | ((unsigned)pr[3] << 16));
    *(uint2*)(WTbf + rb + 32768) =
        make_uint2((unsigned)pi_[0] | ((unsigned)pi_[1] << 16),
                   (unsigned)pi_[2] | ((unsigned)pi_[3] << 16));
  }
}

// Y0p[chunk,c,row=b*4+r,lf] = partial sum: chunks 0-3 = H_RU(n-slice)*WT, chunk 4 = H_BU*F
// grid 320 = (chunk, c). 512 thr = 8 waves: lftile=w&1, mt=w>>1 (16-row M-tile).
__global__ __launch_bounds__(512) void k_y0(
    const float* __restrict__ Rre, const float* __restrict__ Rim,
    const float* __restrict__ Ure, const float* __restrict__ Uim,
    const unsigned short* __restrict__ WTbf, const unsigned short* __restrict__ Fbf,
    float* __restrict__ Y0p)
{
  __shared__ __align__(16) short lA[2][2][64][32];    // 16 KB
  __shared__ __align__(16) short lB[2][2][32][32];    // 8 KB
  const int bid = blockIdx.x;
  const int chunk = bid >> 6, c = bid & 63;
  const int tid = threadIdx.x;
  const int lane = tid & 63, w = tid >> 6;
  const int lftile = w & 1, mt = w >> 1;
  const int kq = lane >> 4, rm = lane & 15;
  const int s_mq = tid & 7, s_nr = tid >> 3;
  const int b_comp = tid >> 7, b_lf = (tid >> 2) & 31, b_q = tid & 3;

  const float* Are; const float* Aim; int ars, ac0;
  const unsigned short* Bb; int brs;
  if (chunk < 4){ Are = Rre; Aim = Rim; ars = 1024; ac0 = chunk * 256; Bb = WTbf; brs = 1024; }
  else          { Are = Ure; Aim = Uim; ars = 256;  ac0 = 0;           Bb = Fbf;  brs = 256;  }
  const size_t arow = ((size_t)((s_nr >> 2) * 64 + c) * 4 + (s_nr & 3)) * ars + ac0;

  f32x4 accRe = {0.f,0.f,0.f,0.f}, accIm = {0.f,0.f,0.f,0.f};
  float4 sRe, sIm; short8 sB;

  auto LOADC = [&](int ck){
    size_t g = arow + ck * 32 + s_mq * 4;
    sRe = *(const float4*)(Are + g);
    sIm = *(const float4*)(Aim + g);
    if (tid < 256){
      size_t gb = ((size_t)(c * 2 + b_comp) * 32 + b_lf) * brs + ac0 + ck * 32 + b_q * 8;
      sB = *(const short8*)(Bb + gb);
    }
  };
  auto WRITEC = [&](int buf){
    int eo = (((s_mq >> 1) ^ (s_nr & 3)) << 3) + (s_mq & 1) * 4;
    unsigned int r0 = (unsigned)f2bf(sRe.x) | ((unsigned)f2bf(sRe.y) << 16);
    unsigned int r1 = (unsigned)f2bf(sRe.z) | ((unsigned)f2bf(sRe.w) << 16);
    *(uint2*)&lA[buf][0][s_nr][eo] = make_uint2(r0, r1);
    unsigned int i0 = (unsigned)f2bf(sIm.x) | ((unsigned)f2bf(sIm.y) << 16);
    unsigned int i1 = (unsigned)f2bf(sIm.z) | ((unsigned)f2bf(sIm.w) << 16);
    *(uint2*)&lA[buf][1][s_nr][eo] = make_uint2(i0, i1);
    if (tid < 256){
      *(short8*)&lB[buf][b_comp][b_lf][(b_q ^ (b_lf & 3)) << 3] = sB;
    }
  };
  auto COMPUTE = [&](int buf){
    int col = lftile * 16 + rm;
    int be = (kq ^ (col & 3)) << 3;
    short8 bRe = *(const short8*)&lB[buf][0][col][be];
    short8 bIm = *(const short8*)&lB[buf][1][col][be];
    short8 bImN;
    #pragma unroll
    for (int i = 0; i < 8; i++) bImN[i] = bIm[i] ^ (short)0x8000;
    int row = mt * 16 + rm;
    int eo = (kq ^ (row & 3)) << 3;
    short8 are = *(const short8*)&lA[buf][0][row][eo];
    short8 aim = *(const short8*)&lA[buf][1][row][eo];
    accRe = __builtin_amdgcn_mfma_f32_16x16x32_bf16(are, bRe,  accRe, 0, 0, 0);
    accRe = __builtin_amdgcn_mfma_f32_16x16x32_bf16(aim, bImN, accRe, 0, 0, 0);
    accIm = __builtin_amdgcn_mfma_f32_16x16x32_bf16(are, bIm,  accIm, 0, 0, 0);
    accIm = __builtin_amdgcn_mfma_f32_16x16x32_bf16(aim, bRe,  accIm, 0, 0, 0);
  };

  LOADC(0); WRITEC(0); __syncthreads();
  for (int ck = 0; ck < 8; ck++){
    int buf = ck & 1;
    if (ck < 7) LOADC(ck + 1);
    COMPUTE(buf);
    if (ck < 7) WRITEC(buf ^ 1);
    __syncthreads();
  }

  #pragma unroll
  for (int r = 0; r < 4; r++){
    int row = mt * 16 + kq * 4 + r;
    int lf = lftile * 16 + rm;
    size_t idx = ((size_t)(chunk * 64 + c) * 64 + row) * 32 + lf;
    float2 o; o.x = accRe[r]; o.y = accIm[r];
    *(float2*)(Y0p + idx * 2) = o;
  }
}

// per (b,l,c) wave: sum 5 partials; power; noise; scatter into x[b,c,rf,t]
__global__ __launch_bounds__(256) void k_fin(
    const float* __restrict__ Y0p,
    const float* __restrict__ nre, const float* __restrict__ nim,
    float* __restrict__ X)
{
  int wid = blockIdx.x * 4 + (threadIdx.x >> 6);  // 8192 = (b,l,c)
  int lane = threadIdx.x & 63;
  int c = wid & 63, l = (wid >> 6) & 7, b = wid >> 9;
  int pair = lane >> 2;
  int r = pair >> 2, f = pair & 3;
  float yR = 0.f, yI = 0.f;
  #pragma unroll
  for (int ch = 0; ch < 5; ch++){
    size_t idx = ((size_t)(ch * 64 + c) * 64 + b * 4 + r) * 32 + l * 4 + f;
    float2 v = *(const float2*)(Y0p + idx * 2);
    yR += v.x; yI += v.y;
  }
  float p = yR * yR + yI * yI;
  p += __shfl_xor(p, 4); p += __shfl_xor(p, 8);
  p += __shfl_xor(p, 16); p += __shfl_xor(p, 32);
  float sc = sqrtf(p * 0.05f);                 // sqrt(power * snr_lin/2), snr_lin=0.1
  if ((lane & 3) == 0){
    size_t ni = ((size_t)((b * 8 + l) * 64 + c) * 4 + r) * 4 + f;
    float oR = yR + nre[ni] * sc;
    float oI = yI + nim[ni] * sc;
    size_t xb = ((size_t)(b * 64 + c) * 16 + pair) * 16;
    X[xb + l]     = oR;   // t = l      (real half)
    X[xb + 8 + l] = oI;   // t = 8 + l  (imag half)
  }
}

// Parallel Polarized Self-Attention, one block per b. b=16,c=64,hw=256.
__global__ __launch_bounds__(256) void k_psa(
    const float* __restrict__ Xin,
    const float* __restrict__ wv_w, const float* __restrict__ wv_b,
    const float* __restrict__ wq_w, const float* __restrict__ wq_b,
    const float* __restrict__ wz_w, const float* __restrict__ wz_b,
    const float* __restrict__ lnw, const float* __restrict__ lnb,
    const float* __restrict__ sv_w, const float* __restrict__ sv_b,
    const float* __restrict__ sq_w, const float* __restrict__ sq_b,
    float* __restrict__ out)
{
  __shared__ float x[64 * 257];
  __shared__ float buf[256];
  __shared__ float xms[64], xqs[64], chw[64], wcomb[64];
  __shared__ float cwzs[32], swqs[32];
  __shared__ float red4[8];
  int b = blockIdx.x, tid = threadIdx.x;
  const float* xin = Xin + (size_t)b * 16384;
  for (int kk = 0; kk < 64; kk++){
    int i = tid + 256 * kk;
    x[(i >> 8) * 257 + (i & 255)] = xin[i];
  }
  __syncthreads();
  if (tid < 64){                                 // row means
    float s = 0.f;
    for (int n = 0; n < 256; n++) s += x[tid * 257 + n];
    xms[tid] = s * (1.f / 256.f);
  }
  // channel softmax over n
  float lq = wq_b[0];
  for (int cc = 0; cc < 64; cc++) lq += wq_w[cc] * x[cc * 257 + tid];
  float mx = lq;
  for (int s = 1; s < 64; s <<= 1) mx = fmaxf(mx, __shfl_xor(mx, s));
  if ((tid & 63) == 0) red4[tid >> 6] = mx;
  __syncthreads();
  mx = fmaxf(fmaxf(red4[0], red4[1]), fmaxf(red4[2], red4[3]));
  float e = expf(lq - mx);
  float se = e;
  for (int s = 1; s < 64; s <<= 1) se += __shfl_xor(se, s);
  if ((tid & 63) == 0) red4[4 + (tid >> 6)] = se;
  __syncthreads();
  se = red4[4] + red4[5] + red4[6] + red4[7];
  buf[tid] = e / se;                             // cwq[n]
  __syncthreads();
  if (tid < 64){                                 // xq[c] = sum_n x*cwq
    float s = 0.f;
    for (int n = 0; n < 256; n++) s += x[tid * 257 + n] * buf[n];
    xqs[tid] = s;
  }
  __syncthreads();
  if (tid < 32){                                 // cwz[k]
    float s = wv_b[tid];
    for (int cc = 0; cc < 64; cc++) s += wv_w[tid * 64 + cc] * xqs[cc];
    cwzs[tid] = s;
  }
  __syncthreads();
  if (tid < 64){                                 // z, LayerNorm, sigmoid
    float z = wz_b[tid];
    for (int k = 0; k < 32; k++) z += cwzs[k] * wz_w[tid * 32 + k];
    float s1 = z, s2 = z * z;
    for (int s = 1; s < 64; s <<= 1){ s1 += __shfl_xor(s1, s); s2 += __shfl_xor(s2, s); }
    float mu = s1 * (1.f / 64.f);
    float var = s2 * (1.f / 64.f) - mu * mu;
    float zn = (z - mu) * rsqrtf(var + 1e-5f) * lnw[tid] + lnb[tid];
    chw[tid] = 1.f / (1.f + expf(-zn));
  }
  if (tid < 32){                                 // spatial softmax over k
    float s = sq_b[tid];
    for (int cc = 0; cc < 64; cc++) s += sq_w[tid * 64 + cc] * xms[cc];
    float m2 = s;
    for (int st = 1; st < 32; st <<= 1) m2 = fmaxf(m2, __shfl_xor(m2, st));
    float ee = expf(s - m2), ss = ee;
    for (int st = 1; st < 32; st <<= 1) ss += __shfl_xor(ss, st);
    swqs[tid] = ee / ss;
  }
  __syncthreads();
  if (tid < 64){                                 // wcomb[c] = sum_k swq*sv_w
    float s = 0.f;
    for (int k = 0; k < 32; k++) s += swqs[k] * sv_w[k * 64 + tid];
    wcomb[tid] = s;
  }
  __syncthreads();
  float bcomb = 0.f;
  for (int k = 0; k < 32; k++) bcomb += swqs[k] * sv_b[k];
  float sz = bcomb;
  for (int cc = 0; cc < 64; cc++) sz += wcomb[cc] * x[cc * 257 + tid];
  float spw = 1.f / (1.f + expf(-sz));
  buf[tid] = spw;                                // reuse buf (cwq dead)
  __syncthreads();
  for (int kk = 0; kk < 64; kk++){
    int i = tid + 256 * kk;
    int cc = i >> 8, n = i & 255;
    out[(size_t)b * 16384 + i] = (buf[n] + chw[cc]) * x[cc * 257 + n];
  }
}

extern "C" void kernel_launch(void* const* d_in, const int* in_sizes, int n_in,
                              void* d_out, int out_size, void* d_ws, size_t ws_size,
                              hipStream_t stream)
{
  if (ws_size < WS_FLOATS * sizeof(float)) return;  // loud failure via validation
  const float* HBRre = (const float*)d_in[0];
  const float* HBRim = (const float*)d_in[1];
  const float* HRUre = (const float*)d_in[2];
  const float* HRUim = (const float*)d_in[3];
  const float* HBUre = (const float*)d_in[4];
  const float* HBUim = (const float*)d_in[5];
  const float* nre   = (const float*)d_in[6];
  const float* nim   = (const float*)d_in[7];
  const float* P1    = (const float*)d_in[8];
  const float* P2    = (const float*)d_in[9];
  const float* PT    = (const float*)d_in[10];
  const float* SA    = (const float*)d_in[11];
  const float* ST    = (const float*)d_in[12];
  const float* wv_w  = (const float*)d_in[13];
  const float* wv_b  = (const float*)d_in[14];
  const float* wq_w  = (const float*)d_in[15];
  const float* wq_b  = (const float*)d_in[16];
  const float* wz_w  = (const float*)d_in[17];
  const float* wz_b  = (const float*)d_in[18];
  const float* lnw   = (const float*)d_in[19];
  const float* lnb   = (const float*)d_in[20];
  const float* sv_w  = (const float*)d_in[21];
  const float* sv_b  = (const float*)d_in[22];
  const float* sq_w  = (const float*)d_in[23];
  const float* sq_b  = (const float*)d_in[24];

  float* ws  = (float*)d_ws;
  float* tre = ws + OFF_THRE;
  float* tim = ws + OFF_THIM;
  unsigned short* fbf  = (unsigned short*)(ws + OFF_FBF);
  unsigned short* wtbf = (unsigned short*)(ws + OFF_WTBF);
  float* y0p = ws + OFF_Y0P;
  float* xb  = ws + OFF_X;

  k_prep<<<4096, 256, 0, stream>>>(P1, P2, PT, SA, ST, tre, tim, fbf);
  k_W<<<2048, 256, 0, stream>>>(HBRre, HBRim, fbf, tre, tim, wtbf);
  k_y0<<<320, 512, 0, stream>>>(HRUre, HRUim, HBUre, HBUim, wtbf, fbf, y0p);
  k_fin<<<2048, 256, 0, stream>>>(y0p, nre, nim, xb);
  k_psa<<<16, 256, 0, stream>>>(xb, wv_w, wv_b, wq_w, wq_b, wz_w, wz_b,
                                lnw, lnb, sv_w, sv_b, sq_w, sq_b, (float*)d_out);
}

// Round 6
// 72.090 us; speedup vs baseline: 1.1537x; 1.1537x over previous
//
#include <hip/hip_runtime.h>
#include <math.h>

// dims: B=16 K=1 NC=64 NR=4 RF=4 L=8 M=256 N=1024 BS_TDD=16 RIS_TDD=16
static constexpr double TWO_PI_D = 6.283185307179586476925287;

// workspace offsets (floats)
static constexpr size_t OFF_THRE = 0;          // theta_re [l][c][n]          524288
static constexpr size_t OFF_THIM = 524288;     // theta_im                    524288
static constexpr size_t OFF_FBF  = 1048576;    // F bf16 [c][comp][lf][m]     1048576 shorts
static constexpr size_t OFF_WTBF = 1572864;    // WT bf16 [c][comp][lf][n]    4194304 shorts
static constexpr size_t OFF_Y0P  = 3670016;    // y0 partials [5][c][row][lf][2] 1310720
static constexpr size_t OFF_X    = 4980736;    // x [b][c][rf][t]             262144
static constexpr size_t WS_FLOATS = 5242880;   // 21 MB

typedef __attribute__((ext_vector_type(8))) short short8;
typedef __attribute__((ext_vector_type(4))) float f32x4;
typedef __attribute__((address_space(3))) unsigned int lds_u32;
typedef const __attribute__((address_space(1))) unsigned int glo_u32;

__device__ __forceinline__ double fm_of(int c){
  return ((double)(c + 1) - 32.5) * (1.0e9 / 64.0) + 1.0e11;
}
__device__ __forceinline__ unsigned short f2bf(float x){
  unsigned int u = __float_as_uint(x);
  return (unsigned short)((u + 0x7FFFu + ((u >> 16) & 1u)) >> 16);
}

// theta (+-1 sign * TTD phase) and F (exp(i SA)/16 * TTD phase), TTD sincos via LDS table
__global__ __launch_bounds__(256) void k_prep(
    const float* __restrict__ P1, const float* __restrict__ P2,
    const float* __restrict__ PT, const float* __restrict__ SA,
    const float* __restrict__ ST,
    float* __restrict__ tre, float* __restrict__ tim, unsigned short* __restrict__ Fbf)
{
  __shared__ double tcs[16], tsn[16];
  int bid = blockIdx.x, tid = threadIdx.x;
  const float TWO_PI_F = 6.2831855f, SEG_F = 3.1415927f;
  if (bid < 2048){                                   // theta: (l,c, n-quarter)
    int l = bid >> 8, c = (bid >> 2) & 63, n0 = (bid & 3) * 256;
    if (tid < 4){
      int ris = (n0 >> 6) + tid;
      double a1 = 5.0e-9 / (1.0 + exp((double)(-PT[l * 16 + ris])));
      sincos(TWO_PI_D * fm_of(c) * a1, &tsn[tid], &tcs[tid]);
    }
    __syncthreads();
    int n = n0 + tid;
    float p1 = P1[l * 1024 + n], p2 = P2[l * 1024 + n];
    int k1 = (int)floorf((TWO_PI_F * p1) / SEG_F);   // BIT=1 -> exp(i*k*pi)=+-1
    int k2 = (int)floorf((TWO_PI_F * p2) / SEG_F);
    float s = ((k1 + k2) & 1) ? -1.f : 1.f;
    int t = (l * 64 + c) * 1024 + n;
    int ti = tid >> 6;
    tre[t] = s * (float)tcs[ti];
    tim[t] = s * (float)tsn[ti];
  } else {                                           // F: (l,c,f) x m
    int bid2 = bid - 2048;
    int l = bid2 >> 8, c = (bid2 >> 2) & 63, f = bid2 & 3;
    int m = tid;
    if (tid < 16){
      double bdel = 5.0e-9 / (1.0 + exp((double)(-ST[((l * 64 + c) * 16 + tid) * 4 + f])));
      sincos(TWO_PI_D * fm_of(c) * bdel, &tsn[tid], &tcs[tid]);
    }
    __syncthreads();
    float sa_ = SA[(size_t)((l * 64 + c) * 256 + m) * 4 + f];
    float ssa, csa;
    sincosf(sa_, &ssa, &csa);                        // exact split: exp(iSA)*exp(i2pi f tau)
    float cb = (float)tcs[m >> 4], sb = (float)tsn[m >> 4];
    size_t base = ((size_t)(c * 2) * 32 + (l * 4 + f)) * 256 + m;
    Fbf[base]        = f2bf((csa * cb - ssa * sb) * 0.0625f);
    Fbf[base + 8192] = f2bf((csa * sb + ssa * cb) * 0.0625f);
  }
}

// WT[c,comp,lf,n] (bf16) = theta[l,c,n] * sum_m H_BR[c,n,m] * F[l,c,m,f]
// One-shot bulk LDS staging: block = (c, 32-row chunk). Each of 64 global_load_lds
// instructions DMAs one FULL contiguous 1KB row (DRAM-sequential). LDS row stride
// 1040B (65 granules) -> per-quarter-wave b128 reads are 2-way (free).
__global__ __launch_bounds__(256, 2) void k_W(
    const float* __restrict__ Hre, const float* __restrict__ Him,
    const unsigned short* __restrict__ Fbf,
    const float* __restrict__ tre, const float* __restrict__ tim,
    unsigned short* __restrict__ WTbf)
{
  __shared__ __align__(16) float lA[16640];   // 64 rows (comp*32+row) x 260 floats = 65 KB
  const int bid = blockIdx.x;
  const int c = bid >> 5;
  const int n0 = (bid & 31) * 32;
  const int tid = threadIdx.x;
  const int lane = tid & 63, w = tid >> 6;

  // ---- bulk stage: 16 DMA instructions per wave, each = 1 full row (1 KB) ----
  const float* hre0 = Hre + ((size_t)c * 1024 + n0) * 256;
  const float* him0 = Him + ((size_t)c * 1024 + n0) * 256;
  #pragma unroll
  for (int i = 0; i < 16; i++){
    int t = w * 16 + i;                       // 0..63: comp = t>>5, row = t&31
    int row = t & 31;
    const float* src = ((t >> 5) ? him0 : hre0) + (size_t)row * 256 + (lane << 2);
    __builtin_amdgcn_global_load_lds((glo_u32*)src, (lds_u32*)&lA[t * 260], 16, 0, 0);
  }
  __syncthreads();                            // one bulk vmcnt(0) drain

  const int lftile = w & 1, rowhalf = w >> 1;
  const int kq = lane >> 4, rm = lane & 15;
  const int lf = lftile * 16 + rm;
  const int rrow = rowhalf * 16 + rm;
  const int nt = n0 + rowhalf * 16;

  const float* aRe = &lA[rrow * 260 + kq * 8];
  const float* aIm = aRe + 32 * 260;
  const unsigned short* fr = Fbf + (size_t)c * 16384 + (size_t)lf * 256 + kq * 8;
  const unsigned short* fi = fr + 8192;

  f32x4 accRe = {0.f,0.f,0.f,0.f}, accIm = {0.f,0.f,0.f,0.f};

  #pragma unroll
  for (int ck = 0; ck < 8; ck++){
    const int mo = ck * 32;
    float4 r0 = *(const float4*)(aRe + mo);
    float4 r1 = *(const float4*)(aRe + mo + 4);
    float4 i0 = *(const float4*)(aIm + mo);
    float4 i1 = *(const float4*)(aIm + mo + 4);
    short8 bre = *(const short8*)(fr + mo);
    short8 bim = *(const short8*)(fi + mo);
    short8 are, aim, bin;
    are[0]=(short)f2bf(r0.x); are[1]=(short)f2bf(r0.y); are[2]=(short)f2bf(r0.z); are[3]=(short)f2bf(r0.w);
    are[4]=(short)f2bf(r1.x); are[5]=(short)f2bf(r1.y); are[6]=(short)f2bf(r1.z); are[7]=(short)f2bf(r1.w);
    aim[0]=(short)f2bf(i0.x); aim[1]=(short)f2bf(i0.y); aim[2]=(short)f2bf(i0.z); aim[3]=(short)f2bf(i0.w);
    aim[4]=(short)f2bf(i1.x); aim[5]=(short)f2bf(i1.y); aim[6]=(short)f2bf(i1.z); aim[7]=(short)f2bf(i1.w);
    #pragma unroll
    for (int j = 0; j < 8; j++) bin[j] = bim[j] ^ (short)0x8000;
    accRe = __builtin_amdgcn_mfma_f32_16x16x32_bf16(are, bre, accRe, 0, 0, 0);
    accRe = __builtin_amdgcn_mfma_f32_16x16x32_bf16(aim, bin, accRe, 0, 0, 0);
    accIm = __builtin_amdgcn_mfma_f32_16x16x32_bf16(are, bim, accIm, 0, 0, 0);
    accIm = __builtin_amdgcn_mfma_f32_16x16x32_bf16(aim, bre, accIm, 0, 0, 0);
  }

  // epilogue: theta-multiply, pack bf16, store WT[c][comp][lf][n]
  // C layout: col(lf)=lane&15, row(n)=nt+kq*4+r
  {
    const int l = lf >> 2;
    unsigned short pr[4], pi_[4];
    #pragma unroll
    for (int r = 0; r < 4; r++){
      size_t ti = (size_t)(l * 64 + c) * 1024 + nt + kq * 4 + r;
      float wr = tre[ti], wi = tim[ti];
      float xr = accRe[r], xi = accIm[r];
      pr[r]  = f2bf(wr * xr - wi * xi);
      pi_[r] = f2bf(wr * xi + wi * xr);
    }
    size_t rb = ((size_t)(c * 2) * 32 + lf) * 1024 + nt + kq * 4;
    *(uint2*)(WTbf + rb) =
        make_uint2((unsigned)pr[0] | ((unsigned)pr[1] << 16),
                   (unsigned)pr[2] | ((unsigned)pr[3] << 16));
    *(uint2*)(WTbf + rb + 32768) =
        make_uint2((unsigned)pi_[0] | ((unsigned)pi_[1] << 16),
                   (unsigned)pi_[2] | ((unsigned)pi_[3] << 16));
  }
}

// Y0p[chunk,c,row=b*4+r,lf] = partial sum: chunks 0-3 = H_RU(n-slice)*WT, chunk 4 = H_BU*F
// grid 320 = (chunk, c). 512 thr = 8 waves: lftile=w&1, mt=w>>1 (16-row M-tile).
__global__ __launch_bounds__(512) void k_y0(
    const float* __restrict__ Rre, const float* __restrict__ Rim,
    const float* __restrict__ Ure, const float* __restrict__ Uim,
    const unsigned short* __restrict__ WTbf, const unsigned short* __restrict__ Fbf,
    float* __restrict__ Y0p)
{
  __shared__ __align__(16) short lA[2][2][64][32];    // 16 KB
  __shared__ __align__(16) short lB[2][2][32][32];    // 8 KB
  const int bid = blockIdx.x;
  const int chunk = bid >> 6, c = bid & 63;
  const int tid = threadIdx.x;
  const int lane = tid & 63, w = tid >> 6;
  const int lftile = w & 1, mt = w >> 1;
  const int kq = lane >> 4, rm = lane & 15;
  const int s_mq = tid & 7, s_nr = tid >> 3;
  const int b_comp = tid >> 7, b_lf = (tid >> 2) & 31, b_q = tid & 3;

  const float* Are; const float* Aim; int ars, ac0;
  const unsigned short* Bb; int brs;
  if (chunk < 4){ Are = Rre; Aim = Rim; ars = 1024; ac0 = chunk * 256; Bb = WTbf; brs = 1024; }
  else          { Are = Ure; Aim = Uim; ars = 256;  ac0 = 0;           Bb = Fbf;  brs = 256;  }
  const size_t arow = ((size_t)((s_nr >> 2) * 64 + c) * 4 + (s_nr & 3)) * ars + ac0;

  f32x4 accRe = {0.f,0.f,0.f,0.f}, accIm = {0.f,0.f,0.f,0.f};
  float4 sRe, sIm; short8 sB;

  auto LOADC = [&](int ck){
    size_t g = arow + ck * 32 + s_mq * 4;
    sRe = *(const float4*)(Are + g);
    sIm = *(const float4*)(Aim + g);
    if (tid < 256){
      size_t gb = ((size_t)(c * 2 + b_comp) * 32 + b_lf) * brs + ac0 + ck * 32 + b_q * 8;
      sB = *(const short8*)(Bb + gb);
    }
  };
  auto WRITEC = [&](int buf){
    int eo = (((s_mq >> 1) ^ (s_nr & 3)) << 3) + (s_mq & 1) * 4;
    unsigned int r0 = (unsigned)f2bf(sRe.x) | ((unsigned)f2bf(sRe.y) << 16);
    unsigned int r1 = (unsigned)f2bf(sRe.z) | ((unsigned)f2bf(sRe.w) << 16);
    *(uint2*)&lA[buf][0][s_nr][eo] = make_uint2(r0, r1);
    unsigned int i0 = (unsigned)f2bf(sIm.x) | ((unsigned)f2bf(sIm.y) << 16);
    unsigned int i1 = (unsigned)f2bf(sIm.z) | ((unsigned)f2bf(sIm.w) << 16);
    *(uint2*)&lA[buf][1][s_nr][eo] = make_uint2(i0, i1);
    if (tid < 256){
      *(short8*)&lB[buf][b_comp][b_lf][(b_q ^ (b_lf & 3)) << 3] = sB;
    }
  };
  auto COMPUTE = [&](int buf){
    int col = lftile * 16 + rm;
    int be = (kq ^ (col & 3)) << 3;
    short8 bRe = *(const short8*)&lB[buf][0][col][be];
    short8 bIm = *(const short8*)&lB[buf][1][col][be];
    short8 bImN;
    #pragma unroll
    for (int i = 0; i < 8; i++) bImN[i] = bIm[i] ^ (short)0x8000;
    int row = mt * 16 + rm;
    int eo = (kq ^ (row & 3)) << 3;
    short8 are = *(const short8*)&lA[buf][0][row][eo];
    short8 aim = *(const short8*)&lA[buf][1][row][eo];
    accRe = __builtin_amdgcn_mfma_f32_16x16x32_bf16(are, bRe,  accRe, 0, 0, 0);
    accRe = __builtin_amdgcn_mfma_f32_16x16x32_bf16(aim, bImN, accRe, 0, 0, 0);
    accIm = __builtin_amdgcn_mfma_f32_16x16x32_bf16(are, bIm,  accIm, 0, 0, 0);
    accIm = __builtin_amdgcn_mfma_f32_16x16x32_bf16(aim, bRe,  accIm, 0, 0, 0);
  };

  LOADC(0); WRITEC(0); __syncthreads();
  for (int ck = 0; ck < 8; ck++){
    int buf = ck & 1;
    if (ck < 7) LOADC(ck + 1);
    COMPUTE(buf);
    if (ck < 7) WRITEC(buf ^ 1);
    __syncthreads();
  }

  #pragma unroll
  for (int r = 0; r < 4; r++){
    int row = mt * 16 + kq * 4 + r;
    int lf = lftile * 16 + rm;
    size_t idx = ((size_t)(chunk * 64 + c) * 64 + row) * 32 + lf;
    float2 o; o.x = accRe[r]; o.y = accIm[r];
    *(float2*)(Y0p + idx * 2) = o;
  }
}

// per (b,l,c) wave: sum 5 partials; power; noise; scatter into x[b,c,rf,t]
__global__ __launch_bounds__(256) void k_fin(
    const float* __restrict__ Y0p,
    const float* __restrict__ nre, const float* __restrict__ nim,
    float* __restrict__ X)
{
  int wid = blockIdx.x * 4 + (threadIdx.x >> 6);  // 8192 = (b,l,c)
  int lane = threadIdx.x & 63;
  int c = wid & 63, l = (wid >> 6) & 7, b = wid >> 9;
  int pair = lane >> 2;
  int r = pair >> 2, f = pair & 3;
  float yR = 0.f, yI = 0.f;
  #pragma unroll
  for (int ch = 0; ch < 5; ch++){
    size_t idx = ((size_t)(ch * 64 + c) * 64 + b * 4 + r) * 32 + l * 4 + f;
    float2 v = *(const float2*)(Y0p + idx * 2);
    yR += v.x; yI += v.y;
  }
  float p = yR * yR + yI * yI;
  p += __shfl_xor(p, 4); p += __shfl_xor(p, 8);
  p += __shfl_xor(p, 16); p += __shfl_xor(p, 32);
  float sc = sqrtf(p * 0.05f);                 // sqrt(power * snr_lin/2), snr_lin=0.1
  if ((lane & 3) == 0){
    size_t ni = ((size_t)((b * 8 + l) * 64 + c) * 4 + r) * 4 + f;
    float oR = yR + nre[ni] * sc;
    float oI = yI + nim[ni] * sc;
    size_t xb = ((size_t)(b * 64 + c) * 16 + pair) * 16;
    X[xb + l]     = oR;   // t = l      (real half)
    X[xb + 8 + l] = oI;   // t = 8 + l  (imag half)
  }
}

// Parallel Polarized Self-Attention, one block per b. b=16,c=64,hw=256.
__global__ __launch_bounds__(256) void k_psa(
    const float* __restrict__ Xin,
    const float* __restrict__ wv_w, const float* __restrict__ wv_b,
    const float* __restrict__ wq_w, const float* __restrict__ wq_b,
    const float* __restrict__ wz_w, const float* __restrict__ wz_b,
    const float* __restrict__ lnw, const float* __restrict__ lnb,
    const float* __restrict__ sv_w, const float* __restrict__ sv_b,
    const float* __restrict__ sq_w, const float* __restrict__ sq_b,
    float* __restrict__ out)
{
  __shared__ float x[64 * 257];
  __shared__ float buf[256];
  __shared__ float xms[64], xqs[64], chw[64], wcomb[64];
  __shared__ float cwzs[32], swqs[32];
  __shared__ float red4[8];
  int b = blockIdx.x, tid = threadIdx.x;
  const float* xin = Xin + (size_t)b * 16384;
  for (int kk = 0; kk < 64; kk++){
    int i = tid + 256 * kk;
    x[(i >> 8) * 257 + (i & 255)] = xin[i];
  }
  __syncthreads();
  if (tid < 64){                                 // row means
    float s = 0.f;
    for (int n = 0; n < 256; n++) s += x[tid * 257 + n];
    xms[tid] = s * (1.f / 256.f);
  }
  // channel softmax over n
  float lq = wq_b[0];
  for (int cc = 0; cc < 64; cc++) lq += wq_w[cc] * x[cc * 257 + tid];
  float mx = lq;
  for (int s = 1; s < 64; s <<= 1) mx = fmaxf(mx, __shfl_xor(mx, s));
  if ((tid & 63) == 0) red4[tid >> 6] = mx;
  __syncthreads();
  mx = fmaxf(fmaxf(red4[0], red4[1]), fmaxf(red4[2], red4[3]));
  float e = expf(lq - mx);
  float se = e;
  for (int s = 1; s < 64; s <<= 1) se += __shfl_xor(se, s);
  if ((tid & 63) == 0) red4[4 + (tid >> 6)] = se;
  __syncthreads();
  se = red4[4] + red4[5] + red4[6] + red4[7];
  buf[tid] = e / se;                             // cwq[n]
  __syncthreads();
  if (tid < 64){                                 // xq[c] = sum_n x*cwq
    float s = 0.f;
    for (int n = 0; n < 256; n++) s += x[tid * 257 + n] * buf[n];
    xqs[tid] = s;
  }
  __syncthreads();
  if (tid < 32){                                 // cwz[k]
    float s = wv_b[tid];
    for (int cc = 0; cc < 64; cc++) s += wv_w[tid * 64 + cc] * xqs[cc];
    cwzs[tid] = s;
  }
  __syncthreads();
  if (tid < 64){                                 // z, LayerNorm, sigmoid
    float z = wz_b[tid];
    for (int k = 0; k < 32; k++) z += cwzs[k] * wz_w[tid * 32 + k];
    float s1 = z, s2 = z * z;
    for (int s = 1; s < 64; s <<= 1){ s1 += __shfl_xor(s1, s); s2 += __shfl_xor(s2, s); }
    float mu = s1 * (1.f / 64.f);
    float var = s2 * (1.f / 64.f) - mu * mu;
    float zn = (z - mu) * rsqrtf(var + 1e-5f) * lnw[tid] + lnb[tid];
    chw[tid] = 1.f / (1.f + expf(-zn));
  }
  if (tid < 32){                                 // spatial softmax over k
    float s = sq_b[tid];
    for (int cc = 0; cc < 64; cc++) s += sq_w[tid * 64 + cc] * xms[cc];
    float m2 = s;
    for (int st = 1; st < 32; st <<= 1) m2 = fmaxf(m2, __shfl_xor(m2, st));
    float ee = expf(s - m2), ss = ee;
    for (int st = 1; st < 32; st <<= 1) ss += __shfl_xor(ss, st);
    swqs[tid] = ee / ss;
  }
  __syncthreads();
  if (tid < 64){                                 // wcomb[c] = sum_k swq*sv_w
    float s = 0.f;
    for (int k = 0; k < 32; k++) s += swqs[k] * sv_w[k * 64 + tid];
    wcomb[tid] = s;
  }
  __syncthreads();
  float bcomb = 0.f;
  for (int k = 0; k < 32; k++) bcomb += swqs[k] * sv_b[k];
  float sz = bcomb;
  for (int cc = 0; cc < 64; cc++) sz += wcomb[cc] * x[cc * 257 + tid];
  float spw = 1.f / (1.f + expf(-sz));
  buf[tid] = spw;                                // reuse buf (cwq dead)
  __syncthreads();
  for (int kk = 0; kk < 64; kk++){
    int i = tid + 256 * kk;
    int cc = i >> 8, n = i & 255;
    out[(size_t)b * 16384 + i] = (buf[n] + chw[cc]) * x[cc * 257 + n];
  }
}

extern "C" void kernel_launch(void* const* d_in, const int* in_sizes, int n_in,
                              void* d_out, int out_size, void* d_ws, size_t ws_size,
                              hipStream_t stream)
{
  if (ws_size < WS_FLOATS * sizeof(float)) return;  // loud failure via validation
  const float* HBRre = (const float*)d_in[0];
  const float* HBRim = (const float*)d_in[1];
  const float* HRUre = (const float*)d_in[2];
  const float* HRUim = (const float*)d_in[3];
  const float* HBUre = (const float*)d_in[4];
  const float* HBUim = (const float*)d_in[5];
  const float* nre   = (const float*)d_in[6];
  const float* nim   = (const float*)d_in[7];
  const float* P1    = (const float*)d_in[8];
  const float* P2    = (const float*)d_in[9];
  const float* PT    = (const float*)d_in[10];
  const float* SA    = (const float*)d_in[11];
  const float* ST    = (const float*)d_in[12];
  const float* wv_w  = (const float*)d_in[13];
  const float* wv_b  = (const float*)d_in[14];
  const float* wq_w  = (const float*)d_in[15];
  const float* wq_b  = (const float*)d_in[16];
  const float* wz_w  = (const float*)d_in[17];
  const float* wz_b  = (const float*)d_in[18];
  const float* lnw   = (const float*)d_in[19];
  const float* lnb   = (const float*)d_in[20];
  const float* sv_w  = (const float*)d_in[21];
  const float* sv_b  = (const float*)d_in[22];
  const float* sq_w  = (const float*)d_in[23];
  const float* sq_b  = (const float*)d_in[24];

  float* ws  = (float*)d_ws;
  float* tre = ws + OFF_THRE;
  float* tim = ws + OFF_THIM;
  unsigned short* fbf  = (unsigned short*)(ws + OFF_FBF);
  unsigned short* wtbf = (unsigned short*)(ws + OFF_WTBF);
  float* y0p = ws + OFF_Y0P;
  float* xb  = ws + OFF_X;

  k_prep<<<4096, 256, 0, stream>>>(P1, P2, PT, SA, ST, tre, tim, fbf);
  k_W<<<2048, 256, 0, stream>>>(HBRre, HBRim, fbf, tre, tim, wtbf);
  k_y0<<<320, 512, 0, stream>>>(HRUre, HRUim, HBUre, HBUim, wtbf, fbf, y0p);
  k_fin<<<2048, 256, 0, stream>>>(y0p, nre, nim, xb);
  k_psa<<<16, 256, 0, stream>>>(xb, wv_w, wv_b, wq_w, wq_b, wz_w, wz_b,
                                lnw, lnb, sv_w, sv_b, sq_w, sq_b, (float*)d_out);
}

// Round 7
// 70.316 us; speedup vs baseline: 1.1828x; 1.0252x over previous
//
#include <hip/hip_runtime.h>
#include <math.h>

// dims: B=16 K=1 NC=64 NR=4 RF=4 L=8 M=256 N=1024 BS_TDD=16 RIS_TDD=16
static constexpr double TWO_PI_D = 6.283185307179586476925287;

// workspace offsets (floats)
static constexpr size_t OFF_THRE = 0;          // theta_re [l][c][n]          524288
static constexpr size_t OFF_THIM = 524288;     // theta_im                    524288
static constexpr size_t OFF_FBF  = 1048576;    // F bf16 [c][comp][lf][m]     1048576 shorts
static constexpr size_t OFF_WTBF = 1572864;    // WT bf16 [c][comp][lf][n]    4194304 shorts
static constexpr size_t OFF_Y0P  = 3670016;    // y0 partials [5][c][row][lf][2] 1310720
static constexpr size_t OFF_X    = 4980736;    // x [b][c][rf][t]             262144
static constexpr size_t WS_FLOATS = 5242880;   // 21 MB

typedef __attribute__((ext_vector_type(8))) short short8;
typedef __attribute__((ext_vector_type(4))) float f32x4;
typedef __attribute__((address_space(3))) unsigned int lds_u32;
typedef const __attribute__((address_space(1))) unsigned int glo_u32;

__device__ __forceinline__ double fm_of(int c){
  return ((double)(c + 1) - 32.5) * (1.0e9 / 64.0) + 1.0e11;
}
__device__ __forceinline__ unsigned short f2bf(float x){
  unsigned int u = __float_as_uint(x);
  return (unsigned short)((u + 0x7FFFu + ((u >> 16) & 1u)) >> 16);
}

// theta (+-1 sign * TTD phase) and F (exp(i SA)/16 * TTD phase), TTD sincos via LDS table
__global__ __launch_bounds__(256) void k_prep(
    const float* __restrict__ P1, const float* __restrict__ P2,
    const float* __restrict__ PT, const float* __restrict__ SA,
    const float* __restrict__ ST,
    float* __restrict__ tre, float* __restrict__ tim, unsigned short* __restrict__ Fbf)
{
  __shared__ double tcs[16], tsn[16];
  int bid = blockIdx.x, tid = threadIdx.x;
  const float TWO_PI_F = 6.2831855f, SEG_F = 3.1415927f;
  if (bid < 2048){                                   // theta: (l,c, n-quarter)
    int l = bid >> 8, c = (bid >> 2) & 63, n0 = (bid & 3) * 256;
    if (tid < 4){
      int ris = (n0 >> 6) + tid;
      double a1 = 5.0e-9 / (1.0 + exp((double)(-PT[l * 16 + ris])));
      sincos(TWO_PI_D * fm_of(c) * a1, &tsn[tid], &tcs[tid]);
    }
    __syncthreads();
    int n = n0 + tid;
    float p1 = P1[l * 1024 + n], p2 = P2[l * 1024 + n];
    int k1 = (int)floorf((TWO_PI_F * p1) / SEG_F);   // BIT=1 -> exp(i*k*pi)=+-1
    int k2 = (int)floorf((TWO_PI_F * p2) / SEG_F);
    float s = ((k1 + k2) & 1) ? -1.f : 1.f;
    int t = (l * 64 + c) * 1024 + n;
    int ti = tid >> 6;
    tre[t] = s * (float)tcs[ti];
    tim[t] = s * (float)tsn[ti];
  } else {                                           // F: (l,c,f) x m
    int bid2 = bid - 2048;
    int l = bid2 >> 8, c = (bid2 >> 2) & 63, f = bid2 & 3;
    int m = tid;
    if (tid < 16){
      double bdel = 5.0e-9 / (1.0 + exp((double)(-ST[((l * 64 + c) * 16 + tid) * 4 + f])));
      sincos(TWO_PI_D * fm_of(c) * bdel, &tsn[tid], &tcs[tid]);
    }
    __syncthreads();
    float sa_ = SA[(size_t)((l * 64 + c) * 256 + m) * 4 + f];
    float ssa, csa;
    sincosf(sa_, &ssa, &csa);                        // exact split: exp(iSA)*exp(i2pi f tau)
    float cb = (float)tcs[m >> 4], sb = (float)tsn[m >> 4];
    size_t base = ((size_t)(c * 2) * 32 + (l * 4 + f)) * 256 + m;
    Fbf[base]        = f2bf((csa * cb - ssa * sb) * 0.0625f);
    Fbf[base + 8192] = f2bf((csa * sb + ssa * cb) * 0.0625f);
  }
}

#define WAITV16 asm volatile("s_waitcnt vmcnt(16)" ::: "memory")
#define WAITV0  asm volatile("s_waitcnt vmcnt(0)" ::: "memory")
#define SBAR    __builtin_amdgcn_s_barrier()

// WT[c,comp,lf,n] (bf16) = theta[l,c,n] * sum_m H_BR[c,n,m] * F[l,c,m,f]
// Pipelined DMA double-buffer: block = (c, 128-row slab), 4 chunks of 32 rows.
// Per iter: issue 16 DMAs for chunk i+1, s_waitcnt vmcnt(16) (drains chunk i only),
// raw s_barrier (no vmcnt(0) drain), compute. F/theta prefetched to regs (older
// than DMAs -> their drain never drains the pipeline). LDS XOR-swizzle (row&7)<<4
// applied to DMA *source* and to read index (both-sides rule).
__global__ __launch_bounds__(256, 1) void k_W(
    const float* __restrict__ Hre, const float* __restrict__ Him,
    const unsigned short* __restrict__ Fbf,
    const float* __restrict__ tre, const float* __restrict__ tim,
    unsigned short* __restrict__ WTbf)
{
  __shared__ __align__(16) float lA[2][2][32][256];   // 128 KB: [buf][comp][row][m]
  const int bid = blockIdx.x;
  const int c = bid >> 3;
  const int slab0 = (bid & 7) * 128;
  const int tid = threadIdx.x;
  const int lane = tid & 63, w = tid >> 6;
  const int lftile = w & 1, rowhalf = w >> 1;
  const int kq = lane >> 4, rm = lane & 15;
  const int lf = lftile * 16 + rm;
  const int l = lf >> 2;

  // ---- register prefetch: F fragments (whole K) + theta for all 4 chunks ----
  const unsigned short* frp = Fbf + (size_t)c * 16384 + (size_t)lf * 256 + kq * 8;
  short8 Fre[8], Fim[8];
  #pragma unroll
  for (int k = 0; k < 8; k++){
    Fre[k] = *(const short8*)(frp + k * 32);
    Fim[k] = *(const short8*)(frp + 8192 + k * 32);
  }
  float thR[16], thI[16];
  {
    size_t tb = (size_t)(l * 64 + c) * 1024 + slab0 + rowhalf * 16 + kq * 4;
    #pragma unroll
    for (int ch = 0; ch < 4; ch++){
      #pragma unroll
      for (int r = 0; r < 4; r++){
        thR[ch * 4 + r] = tre[tb + ch * 32 + r];
        thI[ch * 4 + r] = tim[tb + ch * 32 + r];
      }
    }
  }

  const float* hre0 = Hre + ((size_t)c * 1024 + slab0) * 256;
  const float* him0 = Him + ((size_t)c * 1024 + slab0) * 256;

  auto STAGE = [&](int ch){
    #pragma unroll
    for (int i = 0; i < 16; i++){
      int t = w * 16 + i;                     // 64 row-DMAs: comp=t>>5, row=t&31
      int comp = t >> 5;
      int row = t & 31;
      const float* src = (comp ? him0 : hre0) + ((size_t)(ch * 32 + row)) * 256
                         + ((lane ^ (row & 7)) << 2);   // pre-swizzled source
      __builtin_amdgcn_global_load_lds((glo_u32*)src,
          (lds_u32*)&lA[ch & 1][comp][row][0], 16, 0, 0);
    }
  };

  auto COMP = [&](int ch){
    f32x4 accRe = {0.f,0.f,0.f,0.f}, accIm = {0.f,0.f,0.f,0.f};
    const float* bre = &lA[ch & 1][0][0][0];
    const float* bim = &lA[ch & 1][1][0][0];
    const int row = rowhalf * 16 + rm;
    const int rb = row * 256;
    const int s4 = (row & 7) << 4;            // byte swizzle, 16B granule
    #pragma unroll
    for (int ck = 0; ck < 8; ck++){
      int x0 = ck * 128 + kq * 32;            // byte offset of k-granule 0
      int i0 = (x0 ^ s4) >> 2;
      int i1 = ((x0 + 16) ^ s4) >> 2;
      float4 r0 = *(const float4*)(bre + rb + i0);
      float4 r1 = *(const float4*)(bre + rb + i1);
      float4 m0 = *(const float4*)(bim + rb + i0);
      float4 m1 = *(const float4*)(bim + rb + i1);
      short8 are, aim, bin;
      are[0]=(short)f2bf(r0.x); are[1]=(short)f2bf(r0.y); are[2]=(short)f2bf(r0.z); are[3]=(short)f2bf(r0.w);
      are[4]=(short)f2bf(r1.x); are[5]=(short)f2bf(r1.y); are[6]=(short)f2bf(r1.z); are[7]=(short)f2bf(r1.w);
      aim[0]=(short)f2bf(m0.x); aim[1]=(short)f2bf(m0.y); aim[2]=(short)f2bf(m0.z); aim[3]=(short)f2bf(m0.w);
      aim[4]=(short)f2bf(m1.x); aim[5]=(short)f2bf(m1.y); aim[6]=(short)f2bf(m1.z); aim[7]=(short)f2bf(m1.w);
      #pragma unroll
      for (int j = 0; j < 8; j++) bin[j] = Fim[ck][j] ^ (short)0x8000;
      accRe = __builtin_amdgcn_mfma_f32_16x16x32_bf16(are, Fre[ck], accRe, 0, 0, 0);
      accRe = __builtin_amdgcn_mfma_f32_16x16x32_bf16(aim, bin,     accRe, 0, 0, 0);
      accIm = __builtin_amdgcn_mfma_f32_16x16x32_bf16(are, Fim[ck], accIm, 0, 0, 0);
      accIm = __builtin_amdgcn_mfma_f32_16x16x32_bf16(aim, Fre[ck], accIm, 0, 0, 0);
    }
    // epilogue: theta-multiply (prefetched), pack bf16, store WT[c][comp][lf][n]
    unsigned short pr[4], pi_[4];
    #pragma unroll
    for (int r = 0; r < 4; r++){
      float wr = thR[ch * 4 + r], wi = thI[ch * 4 + r];
      float xr = accRe[r], xi = accIm[r];
      pr[r]  = f2bf(wr * xr - wi * xi);
      pi_[r] = f2bf(wr * xi + wi * xr);
    }
    size_t rb2 = ((size_t)(c * 2) * 32 + lf) * 1024 + slab0 + ch * 32 + rowhalf * 16 + kq * 4;
    *(uint2*)(WTbf + rb2) =
        make_uint2((unsigned)pr[0] | ((unsigned)pr[1] << 16),
                   (unsigned)pr[2] | ((unsigned)pr[3] << 16));
    *(uint2*)(WTbf + rb2 + 32768) =
        make_uint2((unsigned)pi_[0] | ((unsigned)pi_[1] << 16),
                   (unsigned)pi_[2] | ((unsigned)pi_[3] << 16));
  };

  STAGE(0);
  STAGE(1); WAITV16; SBAR; COMP(0); SBAR;
  STAGE(2); WAITV16; SBAR; COMP(1); SBAR;
  STAGE(3); WAITV16; SBAR; COMP(2); SBAR;
  WAITV0;            SBAR; COMP(3);
}

// Y0p[chunk,c,row=b*4+r,lf] = partial sum: chunks 0-3 = H_RU(n-slice)*WT, chunk 4 = H_BU*F
// grid 320 = (chunk, c). 512 thr = 8 waves: lftile=w&1, mt=w>>1 (16-row M-tile).
__global__ __launch_bounds__(512) void k_y0(
    const float* __restrict__ Rre, const float* __restrict__ Rim,
    const float* __restrict__ Ure, const float* __restrict__ Uim,
    const unsigned short* __restrict__ WTbf, const unsigned short* __restrict__ Fbf,
    float* __restrict__ Y0p)
{
  __shared__ __align__(16) short lA[2][2][64][32];    // 16 KB
  __shared__ __align__(16) short lB[2][2][32][32];    // 8 KB
  const int bid = blockIdx.x;
  const int chunk = bid >> 6, c = bid & 63;
  const int tid = threadIdx.x;
  const int lane = tid & 63, w = tid >> 6;
  const int lftile = w & 1, mt = w >> 1;
  const int kq = lane >> 4, rm = lane & 15;
  const int s_mq = tid & 7, s_nr = tid >> 3;
  const int b_comp = tid >> 7, b_lf = (tid >> 2) & 31, b_q = tid & 3;

  const float* Are; const float* Aim; int ars, ac0;
  const unsigned short* Bb; int brs;
  if (chunk < 4){ Are = Rre; Aim = Rim; ars = 1024; ac0 = chunk * 256; Bb = WTbf; brs = 1024; }
  else          { Are = Ure; Aim = Uim; ars = 256;  ac0 = 0;           Bb = Fbf;  brs = 256;  }
  const size_t arow = ((size_t)((s_nr >> 2) * 64 + c) * 4 + (s_nr & 3)) * ars + ac0;

  f32x4 accRe = {0.f,0.f,0.f,0.f}, accIm = {0.f,0.f,0.f,0.f};
  float4 sRe, sIm; short8 sB;

  auto LOADC = [&](int ck){
    size_t g = arow + ck * 32 + s_mq * 4;
    sRe = *(const float4*)(Are + g);
    sIm = *(const float4*)(Aim + g);
    if (tid < 256){
      size_t gb = ((size_t)(c * 2 + b_comp) * 32 + b_lf) * brs + ac0 + ck * 32 + b_q * 8;
      sB = *(const short8*)(Bb + gb);
    }
  };
  auto WRITEC = [&](int buf){
    int eo = (((s_mq >> 1) ^ (s_nr & 3)) << 3) + (s_mq & 1) * 4;
    unsigned int r0 = (unsigned)f2bf(sRe.x) | ((unsigned)f2bf(sRe.y) << 16);
    unsigned int r1 = (unsigned)f2bf(sRe.z) | ((unsigned)f2bf(sRe.w) << 16);
    *(uint2*)&lA[buf][0][s_nr][eo] = make_uint2(r0, r1);
    unsigned int i0 = (unsigned)f2bf(sIm.x) | ((unsigned)f2bf(sIm.y) << 16);
    unsigned int i1 = (unsigned)f2bf(sIm.z) | ((unsigned)f2bf(sIm.w) << 16);
    *(uint2*)&lA[buf][1][s_nr][eo] = make_uint2(i0, i1);
    if (tid < 256){
      *(short8*)&lB[buf][b_comp][b_lf][(b_q ^ (b_lf & 3)) << 3] = sB;
    }
  };
  auto COMPUTE = [&](int buf){
    int col = lftile * 16 + rm;
    int be = (kq ^ (col & 3)) << 3;
    short8 bRe = *(const short8*)&lB[buf][0][col][be];
    short8 bIm = *(const short8*)&lB[buf][1][col][be];
    short8 bImN;
    #pragma unroll
    for (int i = 0; i < 8; i++) bImN[i] = bIm[i] ^ (short)0x8000;
    int row = mt * 16 + rm;
    int eo = (kq ^ (row & 3)) << 3;
    short8 are = *(const short8*)&lA[buf][0][row][eo];
    short8 aim = *(const short8*)&lA[buf][1][row][eo];
    accRe = __builtin_amdgcn_mfma_f32_16x16x32_bf16(are, bRe,  accRe, 0, 0, 0);
    accRe = __builtin_amdgcn_mfma_f32_16x16x32_bf16(aim, bImN, accRe, 0, 0, 0);
    accIm = __builtin_amdgcn_mfma_f32_16x16x32_bf16(are, bIm,  accIm, 0, 0, 0);
    accIm = __builtin_amdgcn_mfma_f32_16x16x32_bf16(aim, bRe,  accIm, 0, 0, 0);
  };

  LOADC(0); WRITEC(0); __syncthreads();
  for (int ck = 0; ck < 8; ck++){
    int buf = ck & 1;
    if (ck < 7) LOADC(ck + 1);
    COMPUTE(buf);
    if (ck < 7) WRITEC(buf ^ 1);
    __syncthreads();
  }

  #pragma unroll
  for (int r = 0; r < 4; r++){
    int row = mt * 16 + kq * 4 + r;
    int lf = lftile * 16 + rm;
    size_t idx = ((size_t)(chunk * 64 + c) * 64 + row) * 32 + lf;
    float2 o; o.x = accRe[r]; o.y = accIm[r];
    *(float2*)(Y0p + idx * 2) = o;
  }
}

// per (b,l,c) wave: sum 5 partials; power; noise; scatter into x[b,c,rf,t]
__global__ __launch_bounds__(256) void k_fin(
    const float* __restrict__ Y0p,
    const float* __restrict__ nre, const float* __restrict__ nim,
    float* __restrict__ X)
{
  int wid = blockIdx.x * 4 + (threadIdx.x >> 6);  // 8192 = (b,l,c)
  int lane = threadIdx.x & 63;
  int c = wid & 63, l = (wid >> 6) & 7, b = wid >> 9;
  int pair = lane >> 2;
  int r = pair >> 2, f = pair & 3;
  float yR = 0.f, yI = 0.f;
  #pragma unroll
  for (int ch = 0; ch < 5; ch++){
    size_t idx = ((size_t)(ch * 64 + c) * 64 + b * 4 + r) * 32 + l * 4 + f;
    float2 v = *(const float2*)(Y0p + idx * 2);
    yR += v.x; yI += v.y;
  }
  float p = yR * yR + yI * yI;
  p += __shfl_xor(p, 4); p += __shfl_xor(p, 8);
  p += __shfl_xor(p, 16); p += __shfl_xor(p, 32);
  float sc = sqrtf(p * 0.05f);                 // sqrt(power * snr_lin/2), snr_lin=0.1
  if ((lane & 3) == 0){
    size_t ni = ((size_t)((b * 8 + l) * 64 + c) * 4 + r) * 4 + f;
    float oR = yR + nre[ni] * sc;
    float oI = yI + nim[ni] * sc;
    size_t xb = ((size_t)(b * 64 + c) * 16 + pair) * 16;
    X[xb + l]     = oR;   // t = l      (real half)
    X[xb + 8 + l] = oI;   // t = 8 + l  (imag half)
  }
}

// Parallel Polarized Self-Attention, one block per b. b=16,c=64,hw=256.
__global__ __launch_bounds__(256) void k_psa(
    const float* __restrict__ Xin,
    const float* __restrict__ wv_w, const float* __restrict__ wv_b,
    const float* __restrict__ wq_w, const float* __restrict__ wq_b,
    const float* __restrict__ wz_w, const float* __restrict__ wz_b,
    const float* __restrict__ lnw, const float* __restrict__ lnb,
    const float* __restrict__ sv_w, const float* __restrict__ sv_b,
    const float* __restrict__ sq_w, const float* __restrict__ sq_b,
    float* __restrict__ out)
{
  __shared__ float x[64 * 257];
  __shared__ float buf[256];
  __shared__ float xms[64], xqs[64], chw[64], wcomb[64];
  __shared__ float cwzs[32], swqs[32];
  __shared__ float red4[8];
  int b = blockIdx.x, tid = threadIdx.x;
  const float* xin = Xin + (size_t)b * 16384;
  for (int kk = 0; kk < 64; kk++){
    int i = tid + 256 * kk;
    x[(i >> 8) * 257 + (i & 255)] = xin[i];
  }
  __syncthreads();
  if (tid < 64){                                 // row means
    float s = 0.f;
    for (int n = 0; n < 256; n++) s += x[tid * 257 + n];
    xms[tid] = s * (1.f / 256.f);
  }
  // channel softmax over n
  float lq = wq_b[0];
  for (int cc = 0; cc < 64; cc++) lq += wq_w[cc] * x[cc * 257 + tid];
  float mx = lq;
  for (int s = 1; s < 64; s <<= 1) mx = fmaxf(mx, __shfl_xor(mx, s));
  if ((tid & 63) == 0) red4[tid >> 6] = mx;
  __syncthreads();
  mx = fmaxf(fmaxf(red4[0], red4[1]), fmaxf(red4[2], red4[3]));
  float e = expf(lq - mx);
  float se = e;
  for (int s = 1; s < 64; s <<= 1) se += __shfl_xor(se, s);
  if ((tid & 63) == 0) red4[4 + (tid >> 6)] = se;
  __syncthreads();
  se = red4[4] + red4[5] + red4[6] + red4[7];
  buf[tid] = e / se;                             // cwq[n]
  __syncthreads();
  if (tid < 64){                                 // xq[c] = sum_n x*cwq
    float s = 0.f;
    for (int n = 0; n < 256; n++) s += x[tid * 257 + n] * buf[n];
    xqs[tid] = s;
  }
  __syncthreads();
  if (tid < 32){                                 // cwz[k]
    float s = wv_b[tid];
    for (int cc = 0; cc < 64; cc++) s += wv_w[tid * 64 + cc] * xqs[cc];
    cwzs[tid] = s;
  }
  __syncthreads();
  if (tid < 64){                                 // z, LayerNorm, sigmoid
    float z = wz_b[tid];
    for (int k = 0; k < 32; k++) z += cwzs[k] * wz_w[tid * 32 + k];
    float s1 = z, s2 = z * z;
    for (int s = 1; s < 64; s <<= 1){ s1 += __shfl_xor(s1, s); s2 += __shfl_xor(s2, s); }
    float mu = s1 * (1.f / 64.f);
    float var = s2 * (1.f / 64.f) - mu * mu;
    float zn = (z - mu) * rsqrtf(var + 1e-5f) * lnw[tid] + lnb[tid];
    chw[tid] = 1.f / (1.f + expf(-zn));
  }
  if (tid < 32){                                 // spatial softmax over k
    float s = sq_b[tid];
    for (int cc = 0; cc < 64; cc++) s += sq_w[tid * 64 + cc] * xms[cc];
    float m2 = s;
    for (int st = 1; st < 32; st <<= 1) m2 = fmaxf(m2, __shfl_xor(m2, st));
    float ee = expf(s - m2), ss = ee;
    for (int st = 1; st < 32; st <<= 1) ss += __shfl_xor(ss, st);
    swqs[tid] = ee / ss;
  }
  __syncthreads();
  if (tid < 64){                                 // wcomb[c] = sum_k swq*sv_w
    float s = 0.f;
    for (int k = 0; k < 32; k++) s += swqs[k] * sv_w[k * 64 + tid];
    wcomb[tid] = s;
  }
  __syncthreads();
  float bcomb = 0.f;
  for (int k = 0; k < 32; k++) bcomb += swqs[k] * sv_b[k];
  float sz = bcomb;
  for (int cc = 0; cc < 64; cc++) sz += wcomb[cc] * x[cc * 257 + tid];
  float spw = 1.f / (1.f + expf(-sz));
  buf[tid] = spw;                                // reuse buf (cwq dead)
  __syncthreads();
  for (int kk = 0; kk < 64; kk++){
    int i = tid + 256 * kk;
    int cc = i >> 8, n = i & 255;
    out[(size_t)b * 16384 + i] = (buf[n] + chw[cc]) * x[cc * 257 + n];
  }
}

extern "C" void kernel_launch(void* const* d_in, const int* in_sizes, int n_in,
                              void* d_out, int out_size, void* d_ws, size_t ws_size,
                              hipStream_t stream)
{
  if (ws_size < WS_FLOATS * sizeof(float)) return;  // loud failure via validation
  const float* HBRre = (const float*)d_in[0];
  const float* HBRim = (const float*)d_in[1];
  const float* HRUre = (const float*)d_in[2];
  const float* HRUim = (const float*)d_in[3];
  const float* HBUre = (const float*)d_in[4];
  const float* HBUim = (const float*)d_in[5];
  const float* nre   = (const float*)d_in[6];
  const float* nim   = (const float*)d_in[7];
  const float* P1    = (const float*)d_in[8];
  const float* P2    = (const float*)d_in[9];
  const float* PT    = (const float*)d_in[10];
  const float* SA    = (const float*)d_in[11];
  const float* ST    = (const float*)d_in[12];
  const float* wv_w  = (const float*)d_in[13];
  const float* wv_b  = (const float*)d_in[14];
  const float* wq_w  = (const float*)d_in[15];
  const float* wq_b  = (const float*)d_in[16];
  const float* wz_w  = (const float*)d_in[17];
  const float* wz_b  = (const float*)d_in[18];
  const float* lnw   = (const float*)d_in[19];
  const float* lnb   = (const float*)d_in[20];
  const float* sv_w  = (const float*)d_in[21];
  const float* sv_b  = (const float*)d_in[22];
  const float* sq_w  = (const float*)d_in[23];
  const float* sq_b  = (const float*)d_in[24];

  float* ws  = (float*)d_ws;
  float* tre = ws + OFF_THRE;
  float* tim = ws + OFF_THIM;
  unsigned short* fbf  = (unsigned short*)(ws + OFF_FBF);
  unsigned short* wtbf = (unsigned short*)(ws + OFF_WTBF);
  float* y0p = ws + OFF_Y0P;
  float* xb  = ws + OFF_X;

  k_prep<<<4096, 256, 0, stream>>>(P1, P2, PT, SA, ST, tre, tim, fbf);
  k_W<<<512, 256, 0, stream>>>(HBRre, HBRim, fbf, tre, tim, wtbf);
  k_y0<<<320, 512, 0, stream>>>(HRUre, HRUim, HBUre, HBUim, wtbf, fbf, y0p);
  k_fin<<<2048, 256, 0, stream>>>(y0p, nre, nim, xb);
  k_psa<<<16, 256, 0, stream>>>(xb, wv_w, wv_b, wq_w, wq_b, wz_w, wz_b,
                                lnw, lnb, sv_w, sv_b, sq_w, sq_b, (float*)d_out);
}

// Round 9
// 69.722 us; speedup vs baseline: 1.1929x; 1.0085x over previous
//
#include <hip/hip_runtime.h>
#include <math.h>

// dims: B=16 K=1 NC=64 NR=4 RF=4 L=8 M=256 N=1024 BS_TDD=16 RIS_TDD=16
static constexpr double TWO_PI_D = 6.283185307179586476925287;

// workspace offsets (floats)
static constexpr size_t OFF_THRE = 0;          // theta_re [l][c][n]          524288
static constexpr size_t OFF_THIM = 524288;     // theta_im                    524288
static constexpr size_t OFF_FBF  = 1048576;    // F bf16 [c][comp][lf][m]     1048576 shorts
static constexpr size_t OFF_WTBF = 1572864;    // WT bf16 [c][comp][lf][n]    4194304 shorts
static constexpr size_t OFF_Y0P  = 3670016;    // y0 partials [5][c][row][lf][2] 1310720
static constexpr size_t OFF_X    = 4980736;    // x [b][c][rf][t]             262144
static constexpr size_t WS_FLOATS = 5242880;   // 21 MB

typedef __attribute__((ext_vector_type(8))) short short8;
typedef __attribute__((ext_vector_type(4))) float f32x4;

__device__ __forceinline__ double fm_of(int c){
  return ((double)(c + 1) - 32.5) * (1.0e9 / 64.0) + 1.0e11;
}
__device__ __forceinline__ unsigned short f2bf(float x){
  unsigned int u = __float_as_uint(x);
  return (unsigned short)((u + 0x7FFFu + ((u >> 16) & 1u)) >> 16);
}

// theta (+-1 sign * TTD phase) and F (exp(i SA)/16 * TTD phase), TTD sincos via LDS table
__global__ __launch_bounds__(256) void k_prep(
    const float* __restrict__ P1, const float* __restrict__ P2,
    const float* __restrict__ PT, const float* __restrict__ SA,
    const float* __restrict__ ST,
    float* __restrict__ tre, float* __restrict__ tim, unsigned short* __restrict__ Fbf)
{
  __shared__ double tcs[16], tsn[16];
  int bid = blockIdx.x, tid = threadIdx.x;
  const float TWO_PI_F = 6.2831855f, SEG_F = 3.1415927f;
  if (bid < 2048){                                   // theta: (l,c, n-quarter)
    int l = bid >> 8, c = (bid >> 2) & 63, n0 = (bid & 3) * 256;
    if (tid < 4){
      int ris = (n0 >> 6) + tid;
      double a1 = 5.0e-9 / (1.0 + exp((double)(-PT[l * 16 + ris])));
      sincos(TWO_PI_D * fm_of(c) * a1, &tsn[tid], &tcs[tid]);
    }
    __syncthreads();
    int n = n0 + tid;
    float p1 = P1[l * 1024 + n], p2 = P2[l * 1024 + n];
    int k1 = (int)floorf((TWO_PI_F * p1) / SEG_F);   // BIT=1 -> exp(i*k*pi)=+-1
    int k2 = (int)floorf((TWO_PI_F * p2) / SEG_F);
    float s = ((k1 + k2) & 1) ? -1.f : 1.f;
    int t = (l * 64 + c) * 1024 + n;
    int ti = tid >> 6;
    tre[t] = s * (float)tcs[ti];
    tim[t] = s * (float)tsn[ti];
  } else {                                           // F: (l,c,f) x m
    int bid2 = bid - 2048;
    int l = bid2 >> 8, c = (bid2 >> 2) & 63, f = bid2 & 3;
    int m = tid;
    if (tid < 16){
      double bdel = 5.0e-9 / (1.0 + exp((double)(-ST[((l * 64 + c) * 16 + tid) * 4 + f])));
      sincos(TWO_PI_D * fm_of(c) * bdel, &tsn[tid], &tcs[tid]);
    }
    __syncthreads();
    float sa_ = SA[(size_t)((l * 64 + c) * 256 + m) * 4 + f];
    float ssa, csa;
    sincosf(sa_, &ssa, &csa);                        // exact split: exp(iSA)*exp(i2pi f tau)
    float cb = (float)tcs[m >> 4], sb = (float)tsn[m >> 4];
    size_t base = ((size_t)(c * 2) * 32 + (l * 4 + f)) * 256 + m;
    Fbf[base]        = f2bf((csa * cb - ssa * sb) * 0.0625f);
    Fbf[base + 8192] = f2bf((csa * sb + ssa * cb) * 0.0625f);
  }
}

// WT[c,comp,lf,n] (bf16) = theta[l,c,n] * sum_m H_BR[c,n,m] * F[l,c,m,f]
// Deep asm register pipeline, NO barriers in hot loop, ~16 waves/CU.
// grid 1024 = (c, 16 chunks of 64 rows); 4 waves; wave = 16 rows x 32 lf.
// 3-stage rotation: 12 global_load_dwordx4 in flight at steady state; consumption
// gated by s_waitcnt vmcnt(N) + sched_barrier(0) (rule-18 fence, no reg ties).
__global__ __launch_bounds__(256, 4) void k_W(
    const float* __restrict__ Hre, const float* __restrict__ Him,
    const unsigned short* __restrict__ Fbf,
    const float* __restrict__ tre, const float* __restrict__ tim,
    unsigned short* __restrict__ WTbf)
{
  __shared__ __align__(16) char lF[2 * 16896];   // [comp][32 lf][528B row] = 33 KB
  const int bid = blockIdx.x;
  const int c = bid >> 4;
  const int nt = (bid & 15) * 64 + (threadIdx.x >> 6) * 16;
  const int lane = threadIdx.x & 63;
  const int kq = lane >> 4, rm = lane & 15;

  // ---- stage F once (32 KB), row stride 528B -> conflict-free b128 reads ----
  {
    const unsigned short* fb = Fbf + (size_t)c * 16384;
    #pragma unroll
    for (int kk = 0; kk < 8; kk++){
      int idx = kk * 256 + threadIdx.x;       // granule id (16B)
      int comp = idx >> 10, lf = (idx >> 5) & 31, gm = idx & 31;
      short8 v = *(const short8*)(fb + comp * 8192 + lf * 256 + gm * 8);
      *(short8*)(lF + comp * 16896 + lf * 528 + gm * 16) = v;
    }
  }
  __syncthreads();                            // drains staging loads (vmcnt=0 baseline)

  const float* hr = Hre + ((size_t)c * 1024 + nt + rm) * 256 + kq * 8;
  const float* hi = Him + ((size_t)c * 1024 + nt + rm) * 256 + kq * 8;
  const char* fb0 = lF + rm * 528 + kq * 16;          // lf tile 0
  const char* fb1 = fb0 + 16 * 528;                   // lf tile 1

  float4 pR0[3], pR1[3], pI0[3], pI1[3];
  f32x4 accRe0 = {0,0,0,0}, accIm0 = {0,0,0,0};
  f32x4 accRe1 = {0,0,0,0}, accIm1 = {0,0,0,0};

#define ISS(S, OA, OB) do{                                                \
    asm volatile("global_load_dwordx4 %0, %2, off offset:" OA "\n\t"      \
                 "global_load_dwordx4 %1, %2, off offset:" OB             \
      : "=&v"(pR0[S]), "=&v"(pR1[S]) : "v"(hr));                          \
    asm volatile("global_load_dwordx4 %0, %2, off offset:" OA "\n\t"      \
                 "global_load_dwordx4 %1, %2, off offset:" OB             \
      : "=&v"(pI0[S]), "=&v"(pI1[S]) : "v"(hi));                          \
  }while(0)

#define WAITC(N) do{                                                      \
    asm volatile("s_waitcnt vmcnt(" N ")" ::: "memory");                  \
    __builtin_amdgcn_sched_barrier(0);                                    \
  }while(0)

#define COMP(S, CK) do{                                                                  \
    short8 bRe0 = *(const short8*)(fb0 + (CK) * 64);                                     \
    short8 bIm0 = *(const short8*)(fb0 + 16896 + (CK) * 64);                             \
    short8 bRe1 = *(const short8*)(fb1 + (CK) * 64);                                     \
    short8 bIm1 = *(const short8*)(fb1 + 16896 + (CK) * 64);                             \
    short8 are, aim, bin0, bin1;                                                         \
    are[0]=(short)f2bf(pR0[S].x); are[1]=(short)f2bf(pR0[S].y);                          \
    are[2]=(short)f2bf(pR0[S].z); are[3]=(short)f2bf(pR0[S].w);                          \
    are[4]=(short)f2bf(pR1[S].x); are[5]=(short)f2bf(pR1[S].y);                          \
    are[6]=(short)f2bf(pR1[S].z); are[7]=(short)f2bf(pR1[S].w);                          \
    aim[0]=(short)f2bf(pI0[S].x); aim[1]=(short)f2bf(pI0[S].y);                          \
    aim[2]=(short)f2bf(pI0[S].z); aim[3]=(short)f2bf(pI0[S].w);                          \
    aim[4]=(short)f2bf(pI1[S].x); aim[5]=(short)f2bf(pI1[S].y);                          \
    aim[6]=(short)f2bf(pI1[S].z); aim[7]=(short)f2bf(pI1[S].w);                          \
    _Pragma("unroll")                                                                    \
    for (int j = 0; j < 8; j++){ bin0[j] = bIm0[j] ^ (short)0x8000;                      \
                                 bin1[j] = bIm1[j] ^ (short)0x8000; }                    \
    accRe0 = __builtin_amdgcn_mfma_f32_16x16x32_bf16(are, bRe0, accRe0, 0, 0, 0);        \
    accRe0 = __builtin_amdgcn_mfma_f32_16x16x32_bf16(aim, bin0, accRe0, 0, 0, 0);        \
    accIm0 = __builtin_amdgcn_mfma_f32_16x16x32_bf16(are, bIm0, accIm0, 0, 0, 0);        \
    accIm0 = __builtin_amdgcn_mfma_f32_16x16x32_bf16(aim, bRe0, accIm0, 0, 0, 0);        \
    accRe1 = __builtin_amdgcn_mfma_f32_16x16x32_bf16(are, bRe1, accRe1, 0, 0, 0);        \
    accRe1 = __builtin_amdgcn_mfma_f32_16x16x32_bf16(aim, bin1, accRe1, 0, 0, 0);        \
    accIm1 = __builtin_amdgcn_mfma_f32_16x16x32_bf16(are, bIm1, accIm1, 0, 0, 0);        \
    accIm1 = __builtin_amdgcn_mfma_f32_16x16x32_bf16(aim, bRe1, accIm1, 0, 0, 0);        \
  }while(0)

  ISS(0, "0",   "16");
  ISS(1, "128", "144");
  ISS(2, "256", "272");
  WAITC("8"); COMP(0, 0); ISS(0, "384", "400");
  WAITC("8"); COMP(1, 1); ISS(1, "512", "528");
  WAITC("8"); COMP(2, 2); ISS(2, "640", "656");
  WAITC("8"); COMP(0, 3); ISS(0, "768", "784");
  WAITC("8"); COMP(1, 4); ISS(1, "896", "912");
  WAITC("8"); COMP(2, 5);
  WAITC("4"); COMP(0, 6);
  WAITC("0"); COMP(1, 7);

#undef ISS
#undef WAITC
#undef COMP

  // epilogue: theta-multiply, pack bf16, store WT[c][comp][lf][n]
  #pragma unroll
  for (int t = 0; t < 2; t++){
    const f32x4 aR = t ? accRe1 : accRe0;
    const f32x4 aI = t ? accIm1 : accIm0;
    int lf = t * 16 + rm;
    int l = lf >> 2;
    unsigned short pr[4], pi_[4];
    #pragma unroll
    for (int r = 0; r < 4; r++){
      size_t ti = (size_t)(l * 64 + c) * 1024 + nt + kq * 4 + r;
      float wr = tre[ti], wi = tim[ti];
      float xr = aR[r], xi = aI[r];
      pr[r]  = f2bf(wr * xr - wi * xi);
      pi_[r] = f2bf(wr * xi + wi * xr);
    }
    size_t rb = ((size_t)(c * 2) * 32 + lf) * 1024 + nt + kq * 4;
    *(uint2*)(WTbf + rb) =
        make_uint2((unsigned)pr[0] | ((unsigned)pr[1] << 16),
                   (unsigned)pr[2] | ((unsigned)pr[3] << 16));
    *(uint2*)(WTbf + rb + 32768) =
        make_uint2((unsigned)pi_[0] | ((unsigned)pi_[1] << 16),
                   (unsigned)pi_[2] | ((unsigned)pi_[3] << 16));
  }
}

// Y0p[chunk,c,row=b*4+r,lf] = partial sum: chunks 0-3 = H_RU(n-slice)*WT, chunk 4 = H_BU*F
// grid 320 = (chunk, c). 512 thr = 8 waves: lftile=w&1, mt=w>>1 (16-row M-tile).
__global__ __launch_bounds__(512) void k_y0(
    const float* __restrict__ Rre, const float* __restrict__ Rim,
    const float* __restrict__ Ure, const float* __restrict__ Uim,
    const unsigned short* __restrict__ WTbf, const unsigned short* __restrict__ Fbf,
    float* __restrict__ Y0p)
{
  __shared__ __align__(16) short lA[2][2][64][32];    // 16 KB
  __shared__ __align__(16) short lB[2][2][32][32];    // 8 KB
  const int bid = blockIdx.x;
  const int chunk = bid >> 6, c = bid & 63;
  const int tid = threadIdx.x;
  const int lane = tid & 63, w = tid >> 6;
  const int lftile = w & 1, mt = w >> 1;
  const int kq = lane >> 4, rm = lane & 15;
  const int s_mq = tid & 7, s_nr = tid >> 3;
  const int b_comp = tid >> 7, b_lf = (tid >> 2) & 31, b_q = tid & 3;

  const float* Are; const float* Aim; int ars, ac0;
  const unsigned short* Bb; int brs;
  if (chunk < 4){ Are = Rre; Aim = Rim; ars = 1024; ac0 = chunk * 256; Bb = WTbf; brs = 1024; }
  else          { Are = Ure; Aim = Uim; ars = 256;  ac0 = 0;           Bb = Fbf;  brs = 256;  }
  const size_t arow = ((size_t)((s_nr >> 2) * 64 + c) * 4 + (s_nr & 3)) * ars + ac0;

  f32x4 accRe = {0.f,0.f,0.f,0.f}, accIm = {0.f,0.f,0.f,0.f};
  float4 sRe, sIm; short8 sB;

  auto LOADC = [&](int ck){
    size_t g = arow + ck * 32 + s_mq * 4;
    sRe = *(const float4*)(Are + g);
    sIm = *(const float4*)(Aim + g);
    if (tid < 256){
      size_t gb = ((size_t)(c * 2 + b_comp) * 32 + b_lf) * brs + ac0 + ck * 32 + b_q * 8;
      sB = *(const short8*)(Bb + gb);
    }
  };
  auto WRITEC = [&](int buf){
    int eo = (((s_mq >> 1) ^ (s_nr & 3)) << 3) + (s_mq & 1) * 4;
    unsigned int r0 = (unsigned)f2bf(sRe.x) | ((unsigned)f2bf(sRe.y) << 16);
    unsigned int r1 = (unsigned)f2bf(sRe.z) | ((unsigned)f2bf(sRe.w) << 16);
    *(uint2*)&lA[buf][0][s_nr][eo] = make_uint2(r0, r1);
    unsigned int i0 = (unsigned)f2bf(sIm.x) | ((unsigned)f2bf(sIm.y) << 16);
    unsigned int i1 = (unsigned)f2bf(sIm.z) | ((unsigned)f2bf(sIm.w) << 16);
    *(uint2*)&lA[buf][1][s_nr][eo] = make_uint2(i0, i1);
    if (tid < 256){
      *(short8*)&lB[buf][b_comp][b_lf][(b_q ^ (b_lf & 3)) << 3] = sB;
    }
  };
  auto COMPUTE = [&](int buf){
    int col = lftile * 16 + rm;
    int be = (kq ^ (col & 3)) << 3;
    short8 bRe = *(const short8*)&lB[buf][0][col][be];
    short8 bIm = *(const short8*)&lB[buf][1][col][be];
    short8 bImN;
    #pragma unroll
    for (int i = 0; i < 8; i++) bImN[i] = bIm[i] ^ (short)0x8000;
    int row = mt * 16 + rm;
    int eo = (kq ^ (row & 3)) << 3;
    short8 are = *(const short8*)&lA[buf][0][row][eo];
    short8 aim = *(const short8*)&lA[buf][1][row][eo];
    accRe = __builtin_amdgcn_mfma_f32_16x16x32_bf16(are, bRe,  accRe, 0, 0, 0);
    accRe = __builtin_amdgcn_mfma_f32_16x16x32_bf16(aim, bImN, accRe, 0, 0, 0);
    accIm = __builtin_amdgcn_mfma_f32_16x16x32_bf16(are, bIm,  accIm, 0, 0, 0);
    accIm = __builtin_amdgcn_mfma_f32_16x16x32_bf16(aim, bRe,  accIm, 0, 0, 0);
  };

  LOADC(0); WRITEC(0); __syncthreads();
  for (int ck = 0; ck < 8; ck++){
    int buf = ck & 1;
    if (ck < 7) LOADC(ck + 1);
    COMPUTE(buf);
    if (ck < 7) WRITEC(buf ^ 1);
    __syncthreads();
  }

  #pragma unroll
  for (int r = 0; r < 4; r++){
    int row = mt * 16 + kq * 4 + r;
    int lf = lftile * 16 + rm;
    size_t idx = ((size_t)(chunk * 64 + c) * 64 + row) * 32 + lf;
    float2 o; o.x = accRe[r]; o.y = accIm[r];
    *(float2*)(Y0p + idx * 2) = o;
  }
}

// per (b,l,c) wave: sum 5 partials; power; noise; scatter into x[b,c,rf,t]
__global__ __launch_bounds__(256) void k_fin(
    const float* __restrict__ Y0p,
    const float* __restrict__ nre, const float* __restrict__ nim,
    float* __restrict__ X)
{
  int wid = blockIdx.x * 4 + (threadIdx.x >> 6);  // 8192 = (b,l,c)
  int lane = threadIdx.x & 63;
  int c = wid & 63, l = (wid >> 6) & 7, b = wid >> 9;
  int pair = lane >> 2;
  int r = pair >> 2, f = pair & 3;
  float yR = 0.f, yI = 0.f;
  #pragma unroll
  for (int ch = 0; ch < 5; ch++){
    size_t idx = ((size_t)(ch * 64 + c) * 64 + b * 4 + r) * 32 + l * 4 + f;
    float2 v = *(const float2*)(Y0p + idx * 2);
    yR += v.x; yI += v.y;
  }
  float p = yR * yR + yI * yI;
  p += __shfl_xor(p, 4); p += __shfl_xor(p, 8);
  p += __shfl_xor(p, 16); p += __shfl_xor(p, 32);
  float sc = sqrtf(p * 0.05f);                 // sqrt(power * snr_lin/2), snr_lin=0.1
  if ((lane & 3) == 0){
    size_t ni = ((size_t)((b * 8 + l) * 64 + c) * 4 + r) * 4 + f;
    float oR = yR + nre[ni] * sc;
    float oI = yI + nim[ni] * sc;
    size_t xb = ((size_t)(b * 64 + c) * 16 + pair) * 16;
    X[xb + l]     = oR;   // t = l      (real half)
    X[xb + 8 + l] = oI;   // t = 8 + l  (imag half)
  }
}

// Parallel Polarized Self-Attention, one block per b. b=16,c=64,hw=256.
__global__ __launch_bounds__(256) void k_psa(
    const float* __restrict__ Xin,
    const float* __restrict__ wv_w, const float* __restrict__ wv_b,
    const float* __restrict__ wq_w, const float* __restrict__ wq_b,
    const float* __restrict__ wz_w, const float* __restrict__ wz_b,
    const float* __restrict__ lnw, const float* __restrict__ lnb,
    const float* __restrict__ sv_w, const float* __restrict__ sv_b,
    const float* __restrict__ sq_w, const float* __restrict__ sq_b,
    float* __restrict__ out)
{
  __shared__ float x[64 * 257];
  __shared__ float buf[256];
  __shared__ float xms[64], xqs[64], chw[64], wcomb[64];
  __shared__ float cwzs[32], swqs[32];
  __shared__ float red4[8];
  int b = blockIdx.x, tid = threadIdx.x;
  const float* xin = Xin + (size_t)b * 16384;
  for (int kk = 0; kk < 64; kk++){
    int i = tid + 256 * kk;
    x[(i >> 8) * 257 + (i & 255)] = xin[i];
  }
  __syncthreads();
  if (tid < 64){                                 // row means
    float s = 0.f;
    for (int n = 0; n < 256; n++) s += x[tid * 257 + n];
    xms[tid] = s * (1.f / 256.f);
  }
  // channel softmax over n
  float lq = wq_b[0];
  for (int cc = 0; cc < 64; cc++) lq += wq_w[cc] * x[cc * 257 + tid];
  float mx = lq;
  for (int s = 1; s < 64; s <<= 1) mx = fmaxf(mx, __shfl_xor(mx, s));
  if ((tid & 63) == 0) red4[tid >> 6] = mx;
  __syncthreads();
  mx = fmaxf(fmaxf(red4[0], red4[1]), fmaxf(red4[2], red4[3]));
  float e = expf(lq - mx);
  float se = e;
  for (int s = 1; s < 64; s <<= 1) se += __shfl_xor(se, s);
  if ((tid & 63) == 0) red4[4 + (tid >> 6)] = se;
  __syncthreads();
  se = red4[4] + red4[5] + red4[6] + red4[7];
  buf[tid] = e / se;                             // cwq[n]
  __syncthreads();
  if (tid < 64){                                 // xq[c] = sum_n x*cwq
    float s = 0.f;
    for (int n = 0; n < 256; n++) s += x[tid * 257 + n] * buf[n];
    xqs[tid] = s;
  }
  __syncthreads();
  if (tid < 32){                                 // cwz[k]
    float s = wv_b[tid];
    for (int cc = 0; cc < 64; cc++) s += wv_w[tid * 64 + cc] * xqs[cc];
    cwzs[tid] = s;
  }
  __syncthreads();
  if (tid < 64){                                 // z, LayerNorm, sigmoid
    float z = wz_b[tid];
    for (int k = 0; k < 32; k++) z += cwzs[k] * wz_w[tid * 32 + k];
    float s1 = z, s2 = z * z;
    for (int s = 1; s < 64; s <<= 1){ s1 += __shfl_xor(s1, s); s2 += __shfl_xor(s2, s); }
    float mu = s1 * (1.f / 64.f);
    float var = s2 * (1.f / 64.f) - mu * mu;
    float zn = (z - mu) * rsqrtf(var + 1e-5f) * lnw[tid] + lnb[tid];
    chw[tid] = 1.f / (1.f + expf(-zn));
  }
  if (tid < 32){                                 // spatial softmax over k
    float s = sq_b[tid];
    for (int cc = 0; cc < 64; cc++) s += sq_w[tid * 64 + cc] * xms[cc];
    float m2 = s;
    for (int st = 1; st < 32; st <<= 1) m2 = fmaxf(m2, __shfl_xor(m2, st));
    float ee = expf(s - m2), ss = ee;
    for (int st = 1; st < 32; st <<= 1) ss += __shfl_xor(ss, st);
    swqs[tid] = ee / ss;
  }
  __syncthreads();
  if (tid < 64){                                 // wcomb[c] = sum_k swq*sv_w
    float s = 0.f;
    for (int k = 0; k < 32; k++) s += swqs[k] * sv_w[k * 64 + tid];
    wcomb[tid] = s;
  }
  __syncthreads();
  float bcomb = 0.f;
  for (int k = 0; k < 32; k++) bcomb += swqs[k] * sv_b[k];
  float sz = bcomb;
  for (int cc = 0; cc < 64; cc++) sz += wcomb[cc] * x[cc * 257 + tid];
  float spw = 1.f / (1.f + expf(-sz));
  buf[tid] = spw;                                // reuse buf (cwq dead)
  __syncthreads();
  for (int kk = 0; kk < 64; kk++){
    int i = tid + 256 * kk;
    int cc = i >> 8, n = i & 255;
    out[(size_t)b * 16384 + i] = (buf[n] + chw[cc]) * x[cc * 257 + n];
  }
}

extern "C" void kernel_launch(void* const* d_in, const int* in_sizes, int n_in,
                              void* d_out, int out_size, void* d_ws, size_t ws_size,
                              hipStream_t stream)
{
  if (ws_size < WS_FLOATS * sizeof(float)) return;  // loud failure via validation
  const float* HBRre = (const float*)d_in[0];
  const float* HBRim = (const float*)d_in[1];
  const float* HRUre = (const float*)d_in[2];
  const float* HRUim = (const float*)d_in[3];
  const float* HBUre = (const float*)d_in[4];
  const float* HBUim = (const float*)d_in[5];
  const float* nre   = (const float*)d_in[6];
  const float* nim   = (const float*)d_in[7];
  const float* P1    = (const float*)d_in[8];
  const float* P2    = (const float*)d_in[9];
  const float* PT    = (const float*)d_in[10];
  const float* SA    = (const float*)d_in[11];
  const float* ST    = (const float*)d_in[12];
  const float* wv_w  = (const float*)d_in[13];
  const float* wv_b  = (const float*)d_in[14];
  const float* wq_w  = (const float*)d_in[15];
  const float* wq_b  = (const float*)d_in[16];
  const float* wz_w  = (const float*)d_in[17];
  const float* wz_b  = (const float*)d_in[18];
  const float* lnw   = (const float*)d_in[19];
  const float* lnb   = (const float*)d_in[20];
  const float* sv_w  = (const float*)d_in[21];
  const float* sv_b  = (const float*)d_in[22];
  const float* sq_w  = (const float*)d_in[23];
  const float* sq_b  = (const float*)d_in[24];

  float* ws  = (float*)d_ws;
  float* tre = ws + OFF_THRE;
  float* tim = ws + OFF_THIM;
  unsigned short* fbf  = (unsigned short*)(ws + OFF_FBF);
  unsigned short* wtbf = (unsigned short*)(ws + OFF_WTBF);
  float* y0p = ws + OFF_Y0P;
  float* xb  = ws + OFF_X;

  k_prep<<<4096, 256, 0, stream>>>(P1, P2, PT, SA, ST, tre, tim, fbf);
  k_W<<<1024, 256, 0, stream>>>(HBRre, HBRim, fbf, tre, tim, wtbf);
  k_y0<<<320, 512, 0, stream>>>(HRUre, HRUim, HBUre, HBUim, wtbf, fbf, y0p);
  k_fin<<<2048, 256, 0, stream>>>(y0p, nre, nim, xb);
  k_psa<<<16, 256, 0, stream>>>(xb, wv_w, wv_b, wq_w, wq_b, wz_w, wz_b,
                                lnw, lnb, sv_w, sv_b, sq_w, sq_b, (float*)d_out);
}

// Round 10
// 62.941 us; speedup vs baseline: 1.3214x; 1.1077x over previous
//
#include <hip/hip_runtime.h>
#include <math.h>

// dims: B=16 K=1 NC=64 NR=4 RF=4 L=8 M=256 N=1024 BS_TDD=16 RIS_TDD=16
static constexpr double TWO_PI_D = 6.283185307179586476925287;

// workspace offsets (floats)
static constexpr size_t OFF_THRE = 0;          // theta_re [l][c][n]          524288
static constexpr size_t OFF_THIM = 524288;     // theta_im                    524288
static constexpr size_t OFF_FBF  = 1048576;    // F bf16 [c][comp][lf][m]     1048576 shorts
static constexpr size_t OFF_WTBF = 1572864;    // WT bf16 [c][comp][lf][n]    4194304 shorts
static constexpr size_t OFF_Y0P  = 3670016;    // y0 partials [5][c][row][lf][2] 1310720
static constexpr size_t OFF_X    = 4980736;    // x [b][c][rf][t]             262144
static constexpr size_t WS_FLOATS = 5242880;   // 21 MB

typedef __attribute__((ext_vector_type(8))) short short8;
typedef __attribute__((ext_vector_type(4))) float f32x4;

__device__ __forceinline__ double fm_of(int c){
  return ((double)(c + 1) - 32.5) * (1.0e9 / 64.0) + 1.0e11;
}
__device__ __forceinline__ unsigned short f2bf(float x){
  unsigned int u = __float_as_uint(x);
  return (unsigned short)((u + 0x7FFFu + ((u >> 16) & 1u)) >> 16);
}

// theta (+-1 sign * TTD phase) and F (exp(i SA)/16 * TTD phase), TTD sincos via LDS table
__global__ __launch_bounds__(256) void k_prep(
    const float* __restrict__ P1, const float* __restrict__ P2,
    const float* __restrict__ PT, const float* __restrict__ SA,
    const float* __restrict__ ST,
    float* __restrict__ tre, float* __restrict__ tim, unsigned short* __restrict__ Fbf)
{
  __shared__ double tcs[16], tsn[16];
  int bid = blockIdx.x, tid = threadIdx.x;
  const float TWO_PI_F = 6.2831855f, SEG_F = 3.1415927f;
  if (bid < 2048){                                   // theta: (l,c, n-quarter)
    int l = bid >> 8, c = (bid >> 2) & 63, n0 = (bid & 3) * 256;
    if (tid < 4){
      int ris = (n0 >> 6) + tid;
      double a1 = 5.0e-9 / (1.0 + exp((double)(-PT[l * 16 + ris])));
      sincos(TWO_PI_D * fm_of(c) * a1, &tsn[tid], &tcs[tid]);
    }
    __syncthreads();
    int n = n0 + tid;
    float p1 = P1[l * 1024 + n], p2 = P2[l * 1024 + n];
    int k1 = (int)floorf((TWO_PI_F * p1) / SEG_F);   // BIT=1 -> exp(i*k*pi)=+-1
    int k2 = (int)floorf((TWO_PI_F * p2) / SEG_F);
    float s = ((k1 + k2) & 1) ? -1.f : 1.f;
    int t = (l * 64 + c) * 1024 + n;
    int ti = tid >> 6;
    tre[t] = s * (float)tcs[ti];
    tim[t] = s * (float)tsn[ti];
  } else {                                           // F: (l,c,f) x m
    int bid2 = bid - 2048;
    int l = bid2 >> 8, c = (bid2 >> 2) & 63, f = bid2 & 3;
    int m = tid;
    if (tid < 16){
      double bdel = 5.0e-9 / (1.0 + exp((double)(-ST[((l * 64 + c) * 16 + tid) * 4 + f])));
      sincos(TWO_PI_D * fm_of(c) * bdel, &tsn[tid], &tcs[tid]);
    }
    __syncthreads();
    float sa_ = SA[(size_t)((l * 64 + c) * 256 + m) * 4 + f];
    float ssa, csa;
    sincosf(sa_, &ssa, &csa);                        // exact split: exp(iSA)*exp(i2pi f tau)
    float cb = (float)tcs[m >> 4], sb = (float)tsn[m >> 4];
    size_t base = ((size_t)(c * 2) * 32 + (l * 4 + f)) * 256 + m;
    Fbf[base]        = f2bf((csa * cb - ssa * sb) * 0.0625f);
    Fbf[base + 8192] = f2bf((csa * sb + ssa * cb) * 0.0625f);
  }
}

// WT[c,comp,lf,n] (bf16) = theta[l,c,n] * sum_m H_BR[c,n,m] * F[l,c,m,f]
// Deep asm register pipeline with NAMED stage registers (no arrays -> no spill),
// launch_bounds(256,2) for VGPR headroom. grid 1024 = (c, 16 chunks of 64 rows);
// 4 waves; wave = 16 rows x 32 lf. 3-stage rotation, counted vmcnt, no hot barriers.
__global__ __launch_bounds__(256, 2) void k_W(
    const float* __restrict__ Hre, const float* __restrict__ Him,
    const unsigned short* __restrict__ Fbf,
    const float* __restrict__ tre, const float* __restrict__ tim,
    unsigned short* __restrict__ WTbf)
{
  __shared__ __align__(16) char lF[2 * 16896];   // [comp][32 lf][528B row] = 33 KB
  const int bid = blockIdx.x;
  const int c = bid >> 4;
  const int nt = (bid & 15) * 64 + (threadIdx.x >> 6) * 16;
  const int lane = threadIdx.x & 63;
  const int kq = lane >> 4, rm = lane & 15;

  // ---- stage F once (32 KB), row stride 528B -> conflict-free b128 reads ----
  {
    const unsigned short* fb = Fbf + (size_t)c * 16384;
    #pragma unroll
    for (int kk = 0; kk < 8; kk++){
      int idx = kk * 256 + threadIdx.x;       // granule id (16B)
      int comp = idx >> 10, lf = (idx >> 5) & 31, gm = idx & 31;
      short8 v = *(const short8*)(fb + comp * 8192 + lf * 256 + gm * 8);
      *(short8*)(lF + comp * 16896 + lf * 528 + gm * 16) = v;
    }
  }
  __syncthreads();                            // drains staging loads (vmcnt=0 baseline)

  const float* hr = Hre + ((size_t)c * 1024 + nt + rm) * 256 + kq * 8;
  const float* hi = Him + ((size_t)c * 1024 + nt + rm) * 256 + kq * 8;
  const char* fb0 = lF + rm * 528 + kq * 16;          // lf tile 0
  const char* fb1 = fb0 + 16 * 528;                   // lf tile 1

  // named stage registers (3 stages x {R0,R1,I0,I1}) -- no arrays, no spill
  float4 aR0, aR1, aI0, aI1;
  float4 bR0, bR1, bI0, bI1;
  float4 cR0, cR1, cI0, cI1;
  f32x4 accRe0 = {0,0,0,0}, accIm0 = {0,0,0,0};
  f32x4 accRe1 = {0,0,0,0}, accIm1 = {0,0,0,0};

#define ISS(R0v, R1v, I0v, I1v, OA, OB) do{                               \
    asm volatile("global_load_dwordx4 %0, %2, off offset:" OA "\n\t"      \
                 "global_load_dwordx4 %1, %2, off offset:" OB             \
      : "=&v"(R0v), "=&v"(R1v) : "v"(hr));                                \
    asm volatile("global_load_dwordx4 %0, %2, off offset:" OA "\n\t"      \
                 "global_load_dwordx4 %1, %2, off offset:" OB             \
      : "=&v"(I0v), "=&v"(I1v) : "v"(hi));                                \
  }while(0)

#define WAITC(N) do{                                                      \
    asm volatile("s_waitcnt vmcnt(" N ")" ::: "memory");                  \
    __builtin_amdgcn_sched_barrier(0);                                    \
  }while(0)

#define COMP(R0v, R1v, I0v, I1v, CK) do{                                                 \
    short8 bRe0 = *(const short8*)(fb0 + (CK) * 64);                                     \
    short8 bIm0 = *(const short8*)(fb0 + 16896 + (CK) * 64);                             \
    short8 bRe1 = *(const short8*)(fb1 + (CK) * 64);                                     \
    short8 bIm1 = *(const short8*)(fb1 + 16896 + (CK) * 64);                             \
    short8 are, aim, bin0, bin1;                                                         \
    are[0]=(short)f2bf(R0v.x); are[1]=(short)f2bf(R0v.y);                                \
    are[2]=(short)f2bf(R0v.z); are[3]=(short)f2bf(R0v.w);                                \
    are[4]=(short)f2bf(R1v.x); are[5]=(short)f2bf(R1v.y);                                \
    are[6]=(short)f2bf(R1v.z); are[7]=(short)f2bf(R1v.w);                                \
    aim[0]=(short)f2bf(I0v.x); aim[1]=(short)f2bf(I0v.y);                                \
    aim[2]=(short)f2bf(I0v.z); aim[3]=(short)f2bf(I0v.w);                                \
    aim[4]=(short)f2bf(I1v.x); aim[5]=(short)f2bf(I1v.y);                                \
    aim[6]=(short)f2bf(I1v.z); aim[7]=(short)f2bf(I1v.w);                                \
    _Pragma("unroll")                                                                    \
    for (int j = 0; j < 8; j++){ bin0[j] = bIm0[j] ^ (short)0x8000;                      \
                                 bin1[j] = bIm1[j] ^ (short)0x8000; }                    \
    accRe0 = __builtin_amdgcn_mfma_f32_16x16x32_bf16(are, bRe0, accRe0, 0, 0, 0);        \
    accRe0 = __builtin_amdgcn_mfma_f32_16x16x32_bf16(aim, bin0, accRe0, 0, 0, 0);        \
    accIm0 = __builtin_amdgcn_mfma_f32_16x16x32_bf16(are, bIm0, accIm0, 0, 0, 0);        \
    accIm0 = __builtin_amdgcn_mfma_f32_16x16x32_bf16(aim, bRe0, accIm0, 0, 0, 0);        \
    accRe1 = __builtin_amdgcn_mfma_f32_16x16x32_bf16(are, bRe1, accRe1, 0, 0, 0);        \
    accRe1 = __builtin_amdgcn_mfma_f32_16x16x32_bf16(aim, bin1, accRe1, 0, 0, 0);        \
    accIm1 = __builtin_amdgcn_mfma_f32_16x16x32_bf16(are, bIm1, accIm1, 0, 0, 0);        \
    accIm1 = __builtin_amdgcn_mfma_f32_16x16x32_bf16(aim, bRe1, accIm1, 0, 0, 0);        \
  }while(0)

  ISS(aR0, aR1, aI0, aI1, "0",   "16");
  ISS(bR0, bR1, bI0, bI1, "128", "144");
  ISS(cR0, cR1, cI0, cI1, "256", "272");
  WAITC("8"); COMP(aR0, aR1, aI0, aI1, 0); ISS(aR0, aR1, aI0, aI1, "384", "400");
  WAITC("8"); COMP(bR0, bR1, bI0, bI1, 1); ISS(bR0, bR1, bI0, bI1, "512", "528");
  WAITC("8"); COMP(cR0, cR1, cI0, cI1, 2); ISS(cR0, cR1, cI0, cI1, "640", "656");
  WAITC("8"); COMP(aR0, aR1, aI0, aI1, 3); ISS(aR0, aR1, aI0, aI1, "768", "784");
  WAITC("8"); COMP(bR0, bR1, bI0, bI1, 4); ISS(bR0, bR1, bI0, bI1, "896", "912");
  WAITC("8"); COMP(cR0, cR1, cI0, cI1, 5);
  WAITC("4"); COMP(aR0, aR1, aI0, aI1, 6);
  WAITC("0"); COMP(bR0, bR1, bI0, bI1, 7);

#undef ISS
#undef WAITC
#undef COMP

  // epilogue: theta-multiply, pack bf16, store WT[c][comp][lf][n]
  #pragma unroll
  for (int t = 0; t < 2; t++){
    const f32x4 aR = t ? accRe1 : accRe0;
    const f32x4 aI = t ? accIm1 : accIm0;
    int lf = t * 16 + rm;
    int l = lf >> 2;
    unsigned short pr[4], pi_[4];
    #pragma unroll
    for (int r = 0; r < 4; r++){
      size_t ti = (size_t)(l * 64 + c) * 1024 + nt + kq * 4 + r;
      float wr = tre[ti], wi = tim[ti];
      float xr = aR[r], xi = aI[r];
      pr[r]  = f2bf(wr * xr - wi * xi);
      pi_[r] = f2bf(wr * xi + wi * xr);
    }
    size_t rb = ((size_t)(c * 2) * 32 + lf) * 1024 + nt + kq * 4;
    *(uint2*)(WTbf + rb) =
        make_uint2((unsigned)pr[0] | ((unsigned)pr[1] << 16),
                   (unsigned)pr[2] | ((unsigned)pr[3] << 16));
    *(uint2*)(WTbf + rb + 32768) =
        make_uint2((unsigned)pi_[0] | ((unsigned)pi_[1] << 16),
                   (unsigned)pi_[2] | ((unsigned)pi_[3] << 16));
  }
}

// Y0p[chunk,c,row=b*4+r,lf] = partial sum: chunks 0-3 = H_RU(n-slice)*WT, chunk 4 = H_BU*F
// grid 320 = (chunk, c). 512 thr = 8 waves: lftile=w&1, mt=w>>1 (16-row M-tile).
__global__ __launch_bounds__(512) void k_y0(
    const float* __restrict__ Rre, const float* __restrict__ Rim,
    const float* __restrict__ Ure, const float* __restrict__ Uim,
    const unsigned short* __restrict__ WTbf, const unsigned short* __restrict__ Fbf,
    float* __restrict__ Y0p)
{
  __shared__ __align__(16) short lA[2][2][64][32];    // 16 KB
  __shared__ __align__(16) short lB[2][2][32][32];    // 8 KB
  const int bid = blockIdx.x;
  const int chunk = bid >> 6, c = bid & 63;
  const int tid = threadIdx.x;
  const int lane = tid & 63, w = tid >> 6;
  const int lftile = w & 1, mt = w >> 1;
  const int kq = lane >> 4, rm = lane & 15;
  const int s_mq = tid & 7, s_nr = tid >> 3;
  const int b_comp = tid >> 7, b_lf = (tid >> 2) & 31, b_q = tid & 3;

  const float* Are; const float* Aim; int ars, ac0;
  const unsigned short* Bb; int brs;
  if (chunk < 4){ Are = Rre; Aim = Rim; ars = 1024; ac0 = chunk * 256; Bb = WTbf; brs = 1024; }
  else          { Are = Ure; Aim = Uim; ars = 256;  ac0 = 0;           Bb = Fbf;  brs = 256;  }
  const size_t arow = ((size_t)((s_nr >> 2) * 64 + c) * 4 + (s_nr & 3)) * ars + ac0;

  f32x4 accRe = {0.f,0.f,0.f,0.f}, accIm = {0.f,0.f,0.f,0.f};
  float4 sRe, sIm; short8 sB;

  auto LOADC = [&](int ck){
    size_t g = arow + ck * 32 + s_mq * 4;
    sRe = *(const float4*)(Are + g);
    sIm = *(const float4*)(Aim + g);
    if (tid < 256){
      size_t gb = ((size_t)(c * 2 + b_comp) * 32 + b_lf) * brs + ac0 + ck * 32 + b_q * 8;
      sB = *(const short8*)(Bb + gb);
    }
  };
  auto WRITEC = [&](int buf){
    int eo = (((s_mq >> 1) ^ (s_nr & 3)) << 3) + (s_mq & 1) * 4;
    unsigned int r0 = (unsigned)f2bf(sRe.x) | ((unsigned)f2bf(sRe.y) << 16);
    unsigned int r1 = (unsigned)f2bf(sRe.z) | ((unsigned)f2bf(sRe.w) << 16);
    *(uint2*)&lA[buf][0][s_nr][eo] = make_uint2(r0, r1);
    unsigned int i0 = (unsigned)f2bf(sIm.x) | ((unsigned)f2bf(sIm.y) << 16);
    unsigned int i1 = (unsigned)f2bf(sIm.z) | ((unsigned)f2bf(sIm.w) << 16);
    *(uint2*)&lA[buf][1][s_nr][eo] = make_uint2(i0, i1);
    if (tid < 256){
      *(short8*)&lB[buf][b_comp][b_lf][(b_q ^ (b_lf & 3)) << 3] = sB;
    }
  };
  auto COMPUTE = [&](int buf){
    int col = lftile * 16 + rm;
    int be = (kq ^ (col & 3)) << 3;
    short8 bRe = *(const short8*)&lB[buf][0][col][be];
    short8 bIm = *(const short8*)&lB[buf][1][col][be];
    short8 bImN;
    #pragma unroll
    for (int i = 0; i < 8; i++) bImN[i] = bIm[i] ^ (short)0x8000;
    int row = mt * 16 + rm;
    int eo = (kq ^ (row & 3)) << 3;
    short8 are = *(const short8*)&lA[buf][0][row][eo];
    short8 aim = *(const short8*)&lA[buf][1][row][eo];
    accRe = __builtin_amdgcn_mfma_f32_16x16x32_bf16(are, bRe,  accRe, 0, 0, 0);
    accRe = __builtin_amdgcn_mfma_f32_16x16x32_bf16(aim, bImN, accRe, 0, 0, 0);
    accIm = __builtin_amdgcn_mfma_f32_16x16x32_bf16(are, bIm,  accIm, 0, 0, 0);
    accIm = __builtin_amdgcn_mfma_f32_16x16x32_bf16(aim, bRe,  accIm, 0, 0, 0);
  };

  LOADC(0); WRITEC(0); __syncthreads();
  for (int ck = 0; ck < 8; ck++){
    int buf = ck & 1;
    if (ck < 7) LOADC(ck + 1);
    COMPUTE(buf);
    if (ck < 7) WRITEC(buf ^ 1);
    __syncthreads();
  }

  #pragma unroll
  for (int r = 0; r < 4; r++){
    int row = mt * 16 + kq * 4 + r;
    int lf = lftile * 16 + rm;
    size_t idx = ((size_t)(chunk * 64 + c) * 64 + row) * 32 + lf;
    float2 o; o.x = accRe[r]; o.y = accIm[r];
    *(float2*)(Y0p + idx * 2) = o;
  }
}

// per (b,l,c) wave: sum 5 partials; power; noise; scatter into x[b,c,rf,t]
__global__ __launch_bounds__(256) void k_fin(
    const float* __restrict__ Y0p,
    const float* __restrict__ nre, const float* __restrict__ nim,
    float* __restrict__ X)
{
  int wid = blockIdx.x * 4 + (threadIdx.x >> 6);  // 8192 = (b,l,c)
  int lane = threadIdx.x & 63;
  int c = wid & 63, l = (wid >> 6) & 7, b = wid >> 9;
  int pair = lane >> 2;
  int r = pair >> 2, f = pair & 3;
  float yR = 0.f, yI = 0.f;
  #pragma unroll
  for (int ch = 0; ch < 5; ch++){
    size_t idx = ((size_t)(ch * 64 + c) * 64 + b * 4 + r) * 32 + l * 4 + f;
    float2 v = *(const float2*)(Y0p + idx * 2);
    yR += v.x; yI += v.y;
  }
  float p = yR * yR + yI * yI;
  p += __shfl_xor(p, 4); p += __shfl_xor(p, 8);
  p += __shfl_xor(p, 16); p += __shfl_xor(p, 32);
  float sc = sqrtf(p * 0.05f);                 // sqrt(power * snr_lin/2), snr_lin=0.1
  if ((lane & 3) == 0){
    size_t ni = ((size_t)((b * 8 + l) * 64 + c) * 4 + r) * 4 + f;
    float oR = yR + nre[ni] * sc;
    float oI = yI + nim[ni] * sc;
    size_t xb = ((size_t)(b * 64 + c) * 16 + pair) * 16;
    X[xb + l]     = oR;   // t = l      (real half)
    X[xb + 8 + l] = oI;   // t = 8 + l  (imag half)
  }
}

// Parallel Polarized Self-Attention, one block per b. b=16,c=64,hw=256.
__global__ __launch_bounds__(256) void k_psa(
    const float* __restrict__ Xin,
    const float* __restrict__ wv_w, const float* __restrict__ wv_b,
    const float* __restrict__ wq_w, const float* __restrict__ wq_b,
    const float* __restrict__ wz_w, const float* __restrict__ wz_b,
    const float* __restrict__ lnw, const float* __restrict__ lnb,
    const float* __restrict__ sv_w, const float* __restrict__ sv_b,
    const float* __restrict__ sq_w, const float* __restrict__ sq_b,
    float* __restrict__ out)
{
  __shared__ float x[64 * 257];
  __shared__ float buf[256];
  __shared__ float xms[64], xqs[64], chw[64], wcomb[64];
  __shared__ float cwzs[32], swqs[32];
  __shared__ float red4[8];
  int b = blockIdx.x, tid = threadIdx.x;
  const float* xin = Xin + (size_t)b * 16384;
  for (int kk = 0; kk < 64; kk++){
    int i = tid + 256 * kk;
    x[(i >> 8) * 257 + (i & 255)] = xin[i];
  }
  __syncthreads();
  if (tid < 64){                                 // row means
    float s = 0.f;
    for (int n = 0; n < 256; n++) s += x[tid * 257 + n];
    xms[tid] = s * (1.f / 256.f);
  }
  // channel softmax over n
  float lq = wq_b[0];
  for (int cc = 0; cc < 64; cc++) lq += wq_w[cc] * x[cc * 257 + tid];
  float mx = lq;
  for (int s = 1; s < 64; s <<= 1) mx = fmaxf(mx, __shfl_xor(mx, s));
  if ((tid & 63) == 0) red4[tid >> 6] = mx;
  __syncthreads();
  mx = fmaxf(fmaxf(red4[0], red4[1]), fmaxf(red4[2], red4[3]));
  float e = expf(lq - mx);
  float se = e;
  for (int s = 1; s < 64; s <<= 1) se += __shfl_xor(se, s);
  if ((tid & 63) == 0) red4[4 + (tid >> 6)] = se;
  __syncthreads();
  se = red4[4] + red4[5] + red4[6] + red4[7];
  buf[tid] = e / se;                             // cwq[n]
  __syncthreads();
  if (tid < 64){                                 // xq[c] = sum_n x*cwq
    float s = 0.f;
    for (int n = 0; n < 256; n++) s += x[tid * 257 + n] * buf[n];
    xqs[tid] = s;
  }
  __syncthreads();
  if (tid < 32){                                 // cwz[k]
    float s = wv_b[tid];
    for (int cc = 0; cc < 64; cc++) s += wv_w[tid * 64 + cc] * xqs[cc];
    cwzs[tid] = s;
  }
  __syncthreads();
  if (tid < 64){                                 // z, LayerNorm, sigmoid
    float z = wz_b[tid];
    for (int k = 0; k < 32; k++) z += cwzs[k] * wz_w[tid * 32 + k];
    float s1 = z, s2 = z * z;
    for (int s = 1; s < 64; s <<= 1){ s1 += __shfl_xor(s1, s); s2 += __shfl_xor(s2, s); }
    float mu = s1 * (1.f / 64.f);
    float var = s2 * (1.f / 64.f) - mu * mu;
    float zn = (z - mu) * rsqrtf(var + 1e-5f) * lnw[tid] + lnb[tid];
    chw[tid] = 1.f / (1.f + expf(-zn));
  }
  if (tid < 32){                                 // spatial softmax over k
    float s = sq_b[tid];
    for (int cc = 0; cc < 64; cc++) s += sq_w[tid * 64 + cc] * xms[cc];
    float m2 = s;
    for (int st = 1; st < 32; st <<= 1) m2 = fmaxf(m2, __shfl_xor(m2, st));
    float ee = expf(s - m2), ss = ee;
    for (int st = 1; st < 32; st <<= 1) ss += __shfl_xor(ss, st);
    swqs[tid] = ee / ss;
  }
  __syncthreads();
  if (tid < 64){                                 // wcomb[c] = sum_k swq*sv_w
    float s = 0.f;
    for (int k = 0; k < 32; k++) s += swqs[k] * sv_w[k * 64 + tid];
    wcomb[tid] = s;
  }
  __syncthreads();
  float bcomb = 0.f;
  for (int k = 0; k < 32; k++) bcomb += swqs[k] * sv_b[k];
  float sz = bcomb;
  for (int cc = 0; cc < 64; cc++) sz += wcomb[cc] * x[cc * 257 + tid];
  float spw = 1.f / (1.f + expf(-sz));
  buf[tid] = spw;                                // reuse buf (cwq dead)
  __syncthreads();
  for (int kk = 0; kk < 64; kk++){
    int i = tid + 256 * kk;
    int cc = i >> 8, n = i & 255;
    out[(size_t)b * 16384 + i] = (buf[n] + chw[cc]) * x[cc * 257 + n];
  }
}

extern "C" void kernel_launch(void* const* d_in, const int* in_sizes, int n_in,
                              void* d_out, int out_size, void* d_ws, size_t ws_size,
                              hipStream_t stream)
{
  if (ws_size < WS_FLOATS * sizeof(float)) return;  // loud failure via validation
  const float* HBRre = (const float*)d_in[0];
  const float* HBRim = (const float*)d_in[1];
  const float* HRUre = (const float*)d_in[2];
  const float* HRUim = (const float*)d_in[3];
  const float* HBUre = (const float*)d_in[4];
  const float* HBUim = (const float*)d_in[5];
  const float* nre   = (const float*)d_in[6];
  const float* nim   = (const float*)d_in[7];
  const float* P1    = (const float*)d_in[8];
  const float* P2    = (const float*)d_in[9];
  const float* PT    = (const float*)d_in[10];
  const float* SA    = (const float*)d_in[11];
  const float* ST    = (const float*)d_in[12];
  const float* wv_w  = (const float*)d_in[13];
  const float* wv_b  = (const float*)d_in[14];
  const float* wq_w  = (const float*)d_in[15];
  const float* wq_b  = (const float*)d_in[16];
  const float* wz_w  = (const float*)d_in[17];
  const float* wz_b  = (const float*)d_in[18];
  const float* lnw   = (const float*)d_in[19];
  const float* lnb   = (const float*)d_in[20];
  const float* sv_w  = (const float*)d_in[21];
  const float* sv_b  = (const float*)d_in[22];
  const float* sq_w  = (const float*)d_in[23];
  const float* sq_b  = (const float*)d_in[24];

  float* ws  = (float*)d_ws;
  float* tre = ws + OFF_THRE;
  float* tim = ws + OFF_THIM;
  unsigned short* fbf  = (unsigned short*)(ws + OFF_FBF);
  unsigned short* wtbf = (unsigned short*)(ws + OFF_WTBF);
  float* y0p = ws + OFF_Y0P;
  float* xb  = ws + OFF_X;

  k_prep<<<4096, 256, 0, stream>>>(P1, P2, PT, SA, ST, tre, tim, fbf);
  k_W<<<1024, 256, 0, stream>>>(HBRre, HBRim, fbf, tre, tim, wtbf);
  k_y0<<<320, 512, 0, stream>>>(HRUre, HRUim, HBUre, HBUim, wtbf, fbf, y0p);
  k_fin<<<2048, 256, 0, stream>>>(y0p, nre, nim, xb);
  k_psa<<<16, 256, 0, stream>>>(xb, wv_w, wv_b, wq_w, wq_b, wz_w, wz_b,
                                lnw, lnb, sv_w, sv_b, sq_w, sq_b, (float*)d_out);
}